// Round 3
// baseline (3045.836 us; speedup 1.0000x reference)
//
#include <hip/hip_runtime.h>
#include <float.h>

#define B_ 16
#define N_ 4096
#define M_ 1024
#define K_ 32
#define FEAT_ 64
#define H_ 128
#define GEO_IN_ 160
#define GEO_MID_ 130
#define FEAT_IN_ 2048

typedef unsigned short u16t;

// ---------------------------------------------------------------- FPS
// One block (1024 thr) per batch. Points + running min-dists in registers.
// Writes fp32 centroids (bit-copies of xyz) directly to d_out.
// Argmax semantics: max dist, tie -> smallest index; no FMA contraction.
__global__ __launch_bounds__(1024) void fps_kernel(
    const float* __restrict__ xyz, float* __restrict__ outc)
{
  const int b = blockIdx.x, tid = threadIdx.x;
  const int lane = tid & 63, wv = tid >> 6;
  const float* xb = xyz + (size_t)b * (N_*3);
  float px[4], py[4], pz[4], dd[4];
#pragma unroll
  for (int j=0;j<4;j++){
    int i = tid + 1024*j;
    px[j]=xb[i*3]; py[j]=xb[i*3+1]; pz[j]=xb[i*3+2];
    dd[j]=FLT_MAX;
  }
  __shared__ float sd[2][16];
  __shared__ int   si[2][16];
  float lx=xb[0], ly=xb[1], lz=xb[2];
  if (tid==0){
    size_t cb=(size_t)b*M_*3;
    outc[cb]=lx; outc[cb+1]=ly; outc[cb+2]=lz;
  }
  for (int t=1;t<M_;t++){
    float bd=-FLT_MAX; int bi=0;
#pragma unroll
    for (int j=0;j<4;j++){
      float dx=__fsub_rn(px[j],lx), dy=__fsub_rn(py[j],ly), dz=__fsub_rn(pz[j],lz);
      float d=__fadd_rn(__fadd_rn(__fmul_rn(dx,dx),__fmul_rn(dy,dy)),__fmul_rn(dz,dz));
      d=fminf(dd[j],d); dd[j]=d;
      if (d>bd){ bd=d; bi=tid+1024*j; }   // j ascending => index ascending; strict > keeps first max
    }
#pragma unroll
    for (int s=1;s<64;s<<=1){
      float od=__shfl_xor(bd,s,64); int oi=__shfl_xor(bi,s,64);
      if (od>bd || (od==bd && oi<bi)){ bd=od; bi=oi; }
    }
    int pb=t&1;
    if (lane==0){ sd[pb][wv]=bd; si[pb][wv]=bi; }
    __syncthreads();
    float cd=sd[pb][0]; int ci=si[pb][0];
#pragma unroll
    for (int w=1;w<16;w++){
      float od=sd[pb][w]; int oi=si[pb][w];
      if (od>cd || (od==cd && oi<ci)){ cd=od; ci=oi; }
    }
    lx=xb[ci*3]; ly=xb[ci*3+1]; lz=xb[ci*3+2];
    if (tid==0){
      size_t cb=((size_t)b*M_+(size_t)t)*3;
      outc[cb]=lx; outc[cb+1]=ly; outc[cb+2]=lz;
    }
  }
}

// ---------------------------------------------------------------- KNN
// One wave per centroid. 64 dists/lane in registers. 32 iterations of
// packed (orderable-dist<<32 | idx) u64 butterfly min == stable top_k
// (max of -d, ties -> smallest index). Centroids read from d_out (exact
// fp32 copies of xyz points).
__global__ __launch_bounds__(256) void knn_kernel(
    const float* __restrict__ xyz, const float* __restrict__ outc,
    u16t* __restrict__ gidx16)
{
  const int w = blockIdx.x*4 + (threadIdx.x>>6);
  const int lane = threadIdx.x & 63;
  const int b = w >> 10;
  const float* xb = xyz + (size_t)b*(N_*3);
  float cx=outc[(size_t)w*3], cy=outc[(size_t)w*3+1], cz=outc[(size_t)w*3+2];
  float c2=__fadd_rn(__fadd_rn(__fmul_rn(cx,cx),__fmul_rn(cy,cy)),__fmul_rn(cz,cz));
  float dl[64];
  float lv=FLT_MAX; int lj=0;
#pragma unroll
  for (int j=0;j<64;j++){
    int i = lane + 64*j;
    float xx=xb[i*3], xy=xb[i*3+1], xz=xb[i*3+2];
    float x2=__fadd_rn(__fadd_rn(__fmul_rn(xx,xx),__fmul_rn(xy,xy)),__fmul_rn(xz,xz));
    float dt=__fadd_rn(__fadd_rn(__fmul_rn(cx,xx),__fmul_rn(cy,xy)),__fmul_rn(cz,xz));
    float d=__fsub_rn(__fadd_rn(c2,x2),__fmul_rn(2.f,dt));
    dl[j]=d;
    if (d<lv){ lv=d; lj=j; }
  }
  const int wb = w*K_;
  for (int k=0;k<K_;k++){
    unsigned u=__float_as_uint(lv);
    u = (u&0x80000000u) ? ~u : (u|0x80000000u);   // order-preserving float->uint
    unsigned long long key = ((unsigned long long)u<<32) | (unsigned)(lane + 64*lj);
#pragma unroll
    for (int s=1;s<64;s<<=1){
      unsigned long long o=__shfl_xor(key,s,64);
      key = (o<key)?o:key;
    }
    int widx=(int)(key & 0xffffffffULL);
    if (lane==0) gidx16[wb+k]=(u16t)widx;
    if ((widx & 63)==lane){
      int slot=widx>>6;
      float nv=FLT_MAX; int nj=0;
#pragma unroll
      for (int j=0;j<64;j++){
        float v=(j==slot)?FLT_MAX:dl[j];
        dl[j]=v;
        if (v<nv){ nv=v; nj=j; }
      }
      lv=nv; lj=nj;
    }
  }
}

// ---------------------------------------------------------------- GEO fused
// 2 groups per block-iteration (256 thr = 2 x 128). Hidden layer in LDS fp32.
// Weight rows streamed from global (80KB + 66.5KB, L2-resident).
__global__ __launch_bounds__(256) void geo_kernel(
    const float* __restrict__ xyz, const float* __restrict__ outc,
    const u16t* __restrict__ gidx16, const float* __restrict__ W1,
    const float* __restrict__ Wout, float* __restrict__ xout)
{
  __shared__ float es[2][GEO_IN_];
  __shared__ float hs[2][H_];
  const int npair=(B_*M_)/2;
  const int half=threadIdx.x>>7, t=threadIdx.x&127;
  for (int pr=blockIdx.x; pr<npair; pr+=gridDim.x){
    int g=pr*2+half;
    int b=g>>10;
    if (t<K_){
      int idx=gidx16[g*K_+t];
      const float* p=xyz + ((size_t)b*N_+(size_t)idx)*3;
      float cx=outc[(size_t)g*3], cy=outc[(size_t)g*3+1], cz=outc[(size_t)g*3+2];
      float dx=__fsub_rn(p[0],cx);
      float dy=__fsub_rn(p[1],cy);
      float dz=__fsub_rn(p[2],cz);
      float sq=__fadd_rn(__fadd_rn(__fmul_rn(dx,dx),__fmul_rn(dy,dy)),__fmul_rn(dz,dz));
      es[half][t*5+0]=dx; es[half][t*5+1]=dy; es[half][t*5+2]=dz;
      es[half][t*5+3]=-1.f; es[half][t*5+4]=__fmul_rn(-0.5f,sq);
    }
    __syncthreads();
    {
      const float* wr=W1 + (size_t)t*GEO_IN_;
      float acc=0.f;
#pragma unroll 8
      for (int i=0;i<GEO_IN_;i++)
        acc=__builtin_fmaf(es[half][i], wr[i], acc);
      hs[half][t]=acc;
    }
    __syncthreads();
    {
      float ss=0.f;
#pragma unroll 8
      for (int i=0;i<H_;i++){ float v=hs[half][i]; ss=__builtin_fmaf(v,v,ss); }
      float e129=__fmul_rn(-0.5f,ss);
      const float* wo=Wout + (size_t)t*GEO_MID_;
      float acc=0.f;
#pragma unroll 8
      for (int i=0;i<H_;i++)
        acc=__builtin_fmaf(hs[half][i], wo[i], acc);
      acc=__builtin_fmaf(-1.f, wo[128], acc);
      acc=__builtin_fmaf(e129, wo[129], acc);
      xout[(size_t)g*256+t]=acc;
    }
    __syncthreads();
  }
}

// ---------------------------------------------------------------- FEAT fused
// 32 groups x 128 h per block; K chunks of 64 (one neighbor per chunk).
// After K-loop: relu(+bias) hidden -> LDS Hs, then layer 2 with Wout rows
// streamed from global (64KB, L2-resident).
__global__ __launch_bounds__(256) void feat_kernel(
    const float* __restrict__ feats, const u16t* __restrict__ gidx16,
    const float* __restrict__ W1, const float* __restrict__ b1,
    const float* __restrict__ Wout, const float* __restrict__ bout,
    float* __restrict__ xout)
{
  __shared__ float Xs[64][33];
  __shared__ float Ws[64][128];
  __shared__ float Hs[32][129];
  const int t=threadIdx.x;
  const int g0=blockIdx.x*32;
  const int gsub=t>>4, hsub=t&15, h0=hsub*8;
  const int gl=t>>3, f0=(t&7)*8;
  const int gld=g0+gl, bld=gld>>10;
  const int hw=t>>1, fw0=(t&1)*32;
  float acc[2][8];
#pragma unroll
  for (int a=0;a<2;a++)
#pragma unroll
    for (int j=0;j<8;j++) acc[a][j]=0.f;

  for (int kk=0;kk<K_;kk++){
    int nidx=gidx16[gld*K_+kk];
    const float* fr=feats + ((size_t)bld*N_+(size_t)nidx)*FEAT_ + f0;
    float4 p0=((const float4*)fr)[0];
    float4 p1=((const float4*)fr)[1];
    const float* wr=W1 + (size_t)hw*FEAT_IN_ + kk*64 + fw0;
    float4 wv[8];
#pragma unroll
    for (int e=0;e<8;e++) wv[e]=((const float4*)wr)[e];
    Xs[f0+0][gl]=p0.x; Xs[f0+1][gl]=p0.y; Xs[f0+2][gl]=p0.z; Xs[f0+3][gl]=p0.w;
    Xs[f0+4][gl]=p1.x; Xs[f0+5][gl]=p1.y; Xs[f0+6][gl]=p1.z; Xs[f0+7][gl]=p1.w;
#pragma unroll
    for (int e=0;e<8;e++){
      Ws[fw0+4*e+0][hw]=wv[e].x;
      Ws[fw0+4*e+1][hw]=wv[e].y;
      Ws[fw0+4*e+2][hw]=wv[e].z;
      Ws[fw0+4*e+3][hw]=wv[e].w;
    }
    __syncthreads();
#pragma unroll 8
    for (int k2=0;k2<64;k2++){
      float x0=Xs[k2][2*gsub], x1=Xs[k2][2*gsub+1];
      const float* wp=&Ws[k2][h0];
      float4 wa=*(const float4*)wp;
      float4 wb=*(const float4*)(wp+4);
      acc[0][0]=__builtin_fmaf(x0,wa.x,acc[0][0]);
      acc[0][1]=__builtin_fmaf(x0,wa.y,acc[0][1]);
      acc[0][2]=__builtin_fmaf(x0,wa.z,acc[0][2]);
      acc[0][3]=__builtin_fmaf(x0,wa.w,acc[0][3]);
      acc[0][4]=__builtin_fmaf(x0,wb.x,acc[0][4]);
      acc[0][5]=__builtin_fmaf(x0,wb.y,acc[0][5]);
      acc[0][6]=__builtin_fmaf(x0,wb.z,acc[0][6]);
      acc[0][7]=__builtin_fmaf(x0,wb.w,acc[0][7]);
      acc[1][0]=__builtin_fmaf(x1,wa.x,acc[1][0]);
      acc[1][1]=__builtin_fmaf(x1,wa.y,acc[1][1]);
      acc[1][2]=__builtin_fmaf(x1,wa.z,acc[1][2]);
      acc[1][3]=__builtin_fmaf(x1,wa.w,acc[1][3]);
      acc[1][4]=__builtin_fmaf(x1,wb.x,acc[1][4]);
      acc[1][5]=__builtin_fmaf(x1,wb.y,acc[1][5]);
      acc[1][6]=__builtin_fmaf(x1,wb.z,acc[1][6]);
      acc[1][7]=__builtin_fmaf(x1,wb.w,acc[1][7]);
    }
    __syncthreads();
  }
  // bias + relu -> Hs
#pragma unroll
  for (int a=0;a<2;a++){
    int glc=gsub*2+a;
#pragma unroll
    for (int j=0;j<8;j++){
      float bv=b1[h0+j];
      Hs[glc][h0+j]=fmaxf(__fadd_rn(acc[a][j],bv),0.f);
    }
  }
  __syncthreads();
  // layer 2: out[g][o] = bout[o] + sum_h Hs[g][h]*Wout[o][h]
  const int o0=h0;
#pragma unroll
  for (int j=0;j<8;j++){
    const float* wr=Wout + (size_t)(o0+j)*H_;
    float s0=0.f, s1=0.f;
#pragma unroll 8
    for (int h=0;h<H_;h++){
      float w=wr[h];
      s0=__builtin_fmaf(Hs[2*gsub][h],  w, s0);
      s1=__builtin_fmaf(Hs[2*gsub+1][h],w, s1);
    }
    float bv=bout[o0+j];
    int ga=g0+2*gsub, gb=ga+1;
    xout[(size_t)ga*256+128+o0+j]=__fadd_rn(s0,bv);
    xout[(size_t)gb*256+128+o0+j]=__fadd_rn(s1,bv);
  }
}

// ----------------------------------------------------------------
extern "C" void kernel_launch(void* const* d_in, const int* in_sizes, int n_in,
                              void* d_out, int out_size, void* d_ws, size_t ws_size,
                              hipStream_t stream) {
  const float* xyz  =(const float*)d_in[0];
  const float* feats=(const float*)d_in[1];
  const float* gW1  =(const float*)d_in[2];
  const float* gWout=(const float*)d_in[3];
  const float* fW1  =(const float*)d_in[4];
  const float* fb1  =(const float*)d_in[5];
  const float* fWout=(const float*)d_in[6];
  const float* fbout=(const float*)d_in[7];
  float* out=(float*)d_out;

  // Workspace: ONLY gidx16 (16384*32 u16 = 1 MB).
  u16t* gidx16=(u16t*)d_ws;
  float* xout = out + (size_t)B_*M_*3;

  fps_kernel <<<dim3(B_),          dim3(1024), 0, stream>>>(xyz, out);
  knn_kernel <<<dim3((B_*M_)/4),   dim3(256),  0, stream>>>(xyz, out, gidx16);
  geo_kernel <<<dim3(2048),        dim3(256),  0, stream>>>(xyz, out, gidx16, gW1, gWout, xout);
  feat_kernel<<<dim3((B_*M_)/32),  dim3(256),  0, stream>>>(feats, gidx16, fW1, fb1, fWout, fbout, xout);
}

// Round 4
// 1814.252 us; speedup vs baseline: 1.6788x; 1.6788x over previous
//
#include <hip/hip_runtime.h>
#include <float.h>

#define B_ 16
#define N_ 4096
#define M_ 1024
#define K_ 32
#define FEAT_ 64
#define H_ 128
#define GEO_IN_ 160
#define GEO_MID_ 130
#define FEAT_IN_ 2048

typedef unsigned short u16t;

// ---------------------------------------------------------------- FPS
// One block (512 thr = 8 waves) per batch. 8 pts/thread in registers.
// Per step: local argmax -> packed u64 key butterfly per wave -> 8-entry LDS
// scan (all threads) -> owner thread publishes winner coords from registers.
// 2 barriers/step, no dependent global loads in the chain.
// Semantics: max dist, tie -> smallest index; no FMA contraction in distance.
__global__ __launch_bounds__(512) void fps_kernel(
    const float* __restrict__ xyz, float* __restrict__ outc)
{
  const int b = blockIdx.x, tid = threadIdx.x;
  const int lane = tid & 63, wv = tid >> 6;
  const float* xb = xyz + (size_t)b * (N_*3);
  float px[8], py[8], pz[8], dd[8];
#pragma unroll
  for (int j=0;j<8;j++){
    int i = tid + 512*j;
    px[j]=xb[i*3]; py[j]=xb[i*3+1]; pz[j]=xb[i*3+2];
    dd[j]=FLT_MAX;
  }
  __shared__ unsigned long long kw[8];
  __shared__ float cw[3];
  float lx=xb[0], ly=xb[1], lz=xb[2];
  if (tid==0){
    size_t cb=(size_t)b*M_*3;
    outc[cb]=lx; outc[cb+1]=ly; outc[cb+2]=lz;
  }
  for (int t=1;t<M_;t++){
    float bd=-FLT_MAX; int bi=0;
#pragma unroll
    for (int j=0;j<8;j++){
      float dx=__fsub_rn(px[j],lx), dy=__fsub_rn(py[j],ly), dz=__fsub_rn(pz[j],lz);
      float d=__fadd_rn(__fadd_rn(__fmul_rn(dx,dx),__fmul_rn(dy,dy)),__fmul_rn(dz,dz));
      d=fminf(dd[j],d); dd[j]=d;
      if (d>bd){ bd=d; bi=tid+512*j; }   // j ascending => idx ascending; strict > keeps first max
    }
    // key: dist (sortable, >=0 so |0x80000000 is monotone) desc, then idx asc
    unsigned long long key=((unsigned long long)(__float_as_uint(bd)|0x80000000u)<<32)
                          | (unsigned)(0xFFFFFFFFu-(unsigned)bi);
#pragma unroll
    for (int s=1;s<64;s<<=1){
      unsigned long long o=__shfl_xor(key,s,64);
      if (o>key) key=o;
    }
    if (lane==0) kw[wv]=key;
    __syncthreads();
    unsigned long long wk=kw[0];
#pragma unroll
    for (int w=1;w<8;w++){
      unsigned long long o=kw[w];
      if (o>wk) wk=o;
    }
    int ci=(int)(0xFFFFFFFFu-(unsigned)wk);
    if (tid==(ci&511)){
      int oj=ci>>9;
      float wx=px[oj], wy=py[oj], wz=pz[oj];
      cw[0]=wx; cw[1]=wy; cw[2]=wz;
      size_t cb=((size_t)b*M_+(size_t)t)*3;
      outc[cb]=wx; outc[cb+1]=wy; outc[cb+2]=wz;
    }
    __syncthreads();
    lx=cw[0]; ly=cw[1]; lz=cw[2];
  }
}

// ---------------------------------------------------------------- KNN
// (unchanged from round 3 — bit-identical selection)
__global__ __launch_bounds__(256) void knn_kernel(
    const float* __restrict__ xyz, const float* __restrict__ outc,
    u16t* __restrict__ gidx16)
{
  const int w = blockIdx.x*4 + (threadIdx.x>>6);
  const int lane = threadIdx.x & 63;
  const int b = w >> 10;
  const float* xb = xyz + (size_t)b*(N_*3);
  float cx=outc[(size_t)w*3], cy=outc[(size_t)w*3+1], cz=outc[(size_t)w*3+2];
  float c2=__fadd_rn(__fadd_rn(__fmul_rn(cx,cx),__fmul_rn(cy,cy)),__fmul_rn(cz,cz));
  float dl[64];
  float lv=FLT_MAX; int lj=0;
#pragma unroll
  for (int j=0;j<64;j++){
    int i = lane + 64*j;
    float xx=xb[i*3], xy=xb[i*3+1], xz=xb[i*3+2];
    float x2=__fadd_rn(__fadd_rn(__fmul_rn(xx,xx),__fmul_rn(xy,xy)),__fmul_rn(xz,xz));
    float dt=__fadd_rn(__fadd_rn(__fmul_rn(cx,xx),__fmul_rn(cy,xy)),__fmul_rn(cz,xz));
    float d=__fsub_rn(__fadd_rn(c2,x2),__fmul_rn(2.f,dt));
    dl[j]=d;
    if (d<lv){ lv=d; lj=j; }
  }
  const int wb = w*K_;
  for (int k=0;k<K_;k++){
    unsigned u=__float_as_uint(lv);
    u = (u&0x80000000u) ? ~u : (u|0x80000000u);
    unsigned long long key = ((unsigned long long)u<<32) | (unsigned)(lane + 64*lj);
#pragma unroll
    for (int s=1;s<64;s<<=1){
      unsigned long long o=__shfl_xor(key,s,64);
      key = (o<key)?o:key;
    }
    int widx=(int)(key & 0xffffffffULL);
    if (lane==0) gidx16[wb+k]=(u16t)widx;
    if ((widx & 63)==lane){
      int slot=widx>>6;
      float nv=FLT_MAX; int nj=0;
#pragma unroll
      for (int j=0;j<64;j++){
        float v=(j==slot)?FLT_MAX:dl[j];
        dl[j]=v;
        if (v<nv){ nv=v; nj=j; }
      }
      lv=nv; lj=nj;
    }
  }
}

// ---------------------------------------------------------------- GEO fused (GEMM-style)
// 32 groups/block, 512 blocks. Es[160][33] embedded A-operand; W chunks staged
// coalesced into Ws[64][128]; hidden transposed Hs[128][33] aliased over Es.
// FMA accumulation order identical to round-3 geo (i asc; k asc then 128,129)
// => bit-identical output.
__global__ __launch_bounds__(256) void geo_kernel(
    const float* __restrict__ xyz, const float* __restrict__ outc,
    const u16t* __restrict__ gidx16, const float* __restrict__ W1,
    const float* __restrict__ Wout, float* __restrict__ xout)
{
  __shared__ float smem[160*33 + 64*128 + 32];   // 54,016 B
  float (*Es)[33]  = (float(*)[33])smem;          // [160][33]
  float (*Hs)[33]  = (float(*)[33])smem;          // [128][33] (alias, used after Es dies)
  float (*Ws)[128] = (float(*)[128])(smem + 160*33);
  float* ssv = smem + 160*33 + 64*128;            // [32]

  const int t=threadIdx.x;
  const int g0=blockIdx.x*32;
  // Phase A: gather + CGA-embed 32 groups x 32 pts
  for (int p=t; p<1024; p+=256){
    int g=p>>5, kk=p&31;
    int gg=g0+g, b=gg>>10;
    int idx=gidx16[gg*K_+kk];
    const float* pt = xyz + ((size_t)b*N_+(size_t)idx)*3;
    const float* cc = outc + (size_t)gg*3;
    float dx=__fsub_rn(pt[0],cc[0]);
    float dy=__fsub_rn(pt[1],cc[1]);
    float dz=__fsub_rn(pt[2],cc[2]);
    float sq=__fadd_rn(__fadd_rn(__fmul_rn(dx,dx),__fmul_rn(dy,dy)),__fmul_rn(dz,dz));
    int r=5*kk;
    Es[r][g]=dx; Es[r+1][g]=dy; Es[r+2][g]=dz;
    Es[r+3][g]=-1.f; Es[r+4][g]=__fmul_rn(-0.5f,sq);
  }
  const int gsub=t>>4, hsub=t&15, h0=hsub*8;
  const int hw=t>>1;
  float acc[2][8];
#pragma unroll
  for (int a=0;a<2;a++)
#pragma unroll
    for (int j=0;j<8;j++) acc[a][j]=0.f;
  __syncthreads();

  // GEMM1: hid[g][h] = sum_{i<160} Es[i][g] * W1[h][i], chunks {64,64,32}
  for (int c=0;c<3;c++){
    int i0=c*64;
    if (c<2){
      int fw0=(t&1)*32;
      const float* wr = W1 + (size_t)hw*GEO_IN_ + i0 + fw0;
      float4 wv[8];
#pragma unroll
      for (int e=0;e<8;e++) wv[e]=((const float4*)wr)[e];
#pragma unroll
      for (int e=0;e<8;e++){
        Ws[fw0+4*e+0][hw]=wv[e].x;
        Ws[fw0+4*e+1][hw]=wv[e].y;
        Ws[fw0+4*e+2][hw]=wv[e].z;
        Ws[fw0+4*e+3][hw]=wv[e].w;
      }
    } else {
      int fw0=(t&1)*16;
      const float* wr = W1 + (size_t)hw*GEO_IN_ + 128 + fw0;
      float4 wv[4];
#pragma unroll
      for (int e=0;e<4;e++) wv[e]=((const float4*)wr)[e];
#pragma unroll
      for (int e=0;e<4;e++){
        Ws[fw0+4*e+0][hw]=wv[e].x;
        Ws[fw0+4*e+1][hw]=wv[e].y;
        Ws[fw0+4*e+2][hw]=wv[e].z;
        Ws[fw0+4*e+3][hw]=wv[e].w;
      }
    }
    __syncthreads();
    int len=(c==2)?32:64;
    for (int k2=0;k2<len;k2++){
      float x0=Es[i0+k2][2*gsub], x1=Es[i0+k2][2*gsub+1];
      const float* wp=&Ws[k2][h0];
      float4 wa=*(const float4*)wp;
      float4 wb=*(const float4*)(wp+4);
      acc[0][0]=__builtin_fmaf(x0,wa.x,acc[0][0]);
      acc[0][1]=__builtin_fmaf(x0,wa.y,acc[0][1]);
      acc[0][2]=__builtin_fmaf(x0,wa.z,acc[0][2]);
      acc[0][3]=__builtin_fmaf(x0,wa.w,acc[0][3]);
      acc[0][4]=__builtin_fmaf(x0,wb.x,acc[0][4]);
      acc[0][5]=__builtin_fmaf(x0,wb.y,acc[0][5]);
      acc[0][6]=__builtin_fmaf(x0,wb.z,acc[0][6]);
      acc[0][7]=__builtin_fmaf(x0,wb.w,acc[0][7]);
      acc[1][0]=__builtin_fmaf(x1,wa.x,acc[1][0]);
      acc[1][1]=__builtin_fmaf(x1,wa.y,acc[1][1]);
      acc[1][2]=__builtin_fmaf(x1,wa.z,acc[1][2]);
      acc[1][3]=__builtin_fmaf(x1,wa.w,acc[1][3]);
      acc[1][4]=__builtin_fmaf(x1,wb.x,acc[1][4]);
      acc[1][5]=__builtin_fmaf(x1,wb.y,acc[1][5]);
      acc[1][6]=__builtin_fmaf(x1,wb.z,acc[1][6]);
      acc[1][7]=__builtin_fmaf(x1,wb.w,acc[1][7]);
    }
    __syncthreads();
  }
  // hidden -> Hs (transposed), aliases Es (all Es reads done: barrier above)
#pragma unroll
  for (int a=0;a<2;a++)
#pragma unroll
    for (int j=0;j<8;j++)
      Hs[h0+j][2*gsub+a]=acc[a][j];
  __syncthreads();
  // ss per group (sequential over h, matches ref order); overlap chunk-0 staging
  if (t<32){
    float ss=0.f;
    for (int h=0;h<H_;h++){ float v=Hs[h][t]; ss=__builtin_fmaf(v,v,ss); }
    ssv[t]=__fmul_rn(-0.5f,ss);
  }
#pragma unroll
  for (int a=0;a<2;a++)
#pragma unroll
    for (int j=0;j<8;j++) acc[a][j]=0.f;
  // GEMM2: out[g][o] = sum_{k<128} Hs[k][g]*Wout[o][k]  (+ cols 128,129 epilogue)
  for (int c=0;c<2;c++){
    int i0=c*64;
    int fw0=(t&1)*32;
    const float* wr = Wout + (size_t)hw*GEO_MID_ + i0 + fw0;
    float2 wv2[16];
#pragma unroll
    for (int e=0;e<16;e++) wv2[e]=((const float2*)wr)[e];
    __syncthreads();   // previous Ws readers done
#pragma unroll
    for (int e=0;e<16;e++){
      Ws[fw0+2*e+0][hw]=wv2[e].x;
      Ws[fw0+2*e+1][hw]=wv2[e].y;
    }
    __syncthreads();
    for (int k2=0;k2<64;k2++){
      float x0=Hs[i0+k2][2*gsub], x1=Hs[i0+k2][2*gsub+1];
      const float* wp=&Ws[k2][h0];
      float4 wa=*(const float4*)wp;
      float4 wb=*(const float4*)(wp+4);
      acc[0][0]=__builtin_fmaf(x0,wa.x,acc[0][0]);
      acc[0][1]=__builtin_fmaf(x0,wa.y,acc[0][1]);
      acc[0][2]=__builtin_fmaf(x0,wa.z,acc[0][2]);
      acc[0][3]=__builtin_fmaf(x0,wa.w,acc[0][3]);
      acc[0][4]=__builtin_fmaf(x0,wb.x,acc[0][4]);
      acc[0][5]=__builtin_fmaf(x0,wb.y,acc[0][5]);
      acc[0][6]=__builtin_fmaf(x0,wb.z,acc[0][6]);
      acc[0][7]=__builtin_fmaf(x0,wb.w,acc[0][7]);
      acc[1][0]=__builtin_fmaf(x1,wa.x,acc[1][0]);
      acc[1][1]=__builtin_fmaf(x1,wa.y,acc[1][1]);
      acc[1][2]=__builtin_fmaf(x1,wa.z,acc[1][2]);
      acc[1][3]=__builtin_fmaf(x1,wa.w,acc[1][3]);
      acc[1][4]=__builtin_fmaf(x1,wb.x,acc[1][4]);
      acc[1][5]=__builtin_fmaf(x1,wb.y,acc[1][5]);
      acc[1][6]=__builtin_fmaf(x1,wb.z,acc[1][6]);
      acc[1][7]=__builtin_fmaf(x1,wb.w,acc[1][7]);
    }
  }
  // epilogue: cols 128 (x -1) and 129 (x -0.5*ss), then store
#pragma unroll
  for (int j=0;j<8;j++){
    int o=h0+j;
    float2 we=*(const float2*)(Wout + (size_t)o*GEO_MID_ + 128);
#pragma unroll
    for (int a=0;a<2;a++){
      float v=acc[a][j];
      v=__builtin_fmaf(-1.f, we.x, v);
      v=__builtin_fmaf(ssv[2*gsub+a], we.y, v);
      xout[(size_t)(g0+2*gsub+a)*256 + o]=v;
    }
  }
}

// ---------------------------------------------------------------- FEAT fused
// (unchanged from round 3)
__global__ __launch_bounds__(256) void feat_kernel(
    const float* __restrict__ feats, const u16t* __restrict__ gidx16,
    const float* __restrict__ W1, const float* __restrict__ b1,
    const float* __restrict__ Wout, const float* __restrict__ bout,
    float* __restrict__ xout)
{
  __shared__ float Xs[64][33];
  __shared__ float Ws[64][128];
  __shared__ float Hs[32][129];
  const int t=threadIdx.x;
  const int g0=blockIdx.x*32;
  const int gsub=t>>4, hsub=t&15, h0=hsub*8;
  const int gl=t>>3, f0=(t&7)*8;
  const int gld=g0+gl, bld=gld>>10;
  const int hw=t>>1, fw0=(t&1)*32;
  float acc[2][8];
#pragma unroll
  for (int a=0;a<2;a++)
#pragma unroll
    for (int j=0;j<8;j++) acc[a][j]=0.f;

  for (int kk=0;kk<K_;kk++){
    int nidx=gidx16[gld*K_+kk];
    const float* fr=feats + ((size_t)bld*N_+(size_t)nidx)*FEAT_ + f0;
    float4 p0=((const float4*)fr)[0];
    float4 p1=((const float4*)fr)[1];
    const float* wr=W1 + (size_t)hw*FEAT_IN_ + kk*64 + fw0;
    float4 wv[8];
#pragma unroll
    for (int e=0;e<8;e++) wv[e]=((const float4*)wr)[e];
    Xs[f0+0][gl]=p0.x; Xs[f0+1][gl]=p0.y; Xs[f0+2][gl]=p0.z; Xs[f0+3][gl]=p0.w;
    Xs[f0+4][gl]=p1.x; Xs[f0+5][gl]=p1.y; Xs[f0+6][gl]=p1.z; Xs[f0+7][gl]=p1.w;
#pragma unroll
    for (int e=0;e<8;e++){
      Ws[fw0+4*e+0][hw]=wv[e].x;
      Ws[fw0+4*e+1][hw]=wv[e].y;
      Ws[fw0+4*e+2][hw]=wv[e].z;
      Ws[fw0+4*e+3][hw]=wv[e].w;
    }
    __syncthreads();
#pragma unroll 8
    for (int k2=0;k2<64;k2++){
      float x0=Xs[k2][2*gsub], x1=Xs[k2][2*gsub+1];
      const float* wp=&Ws[k2][h0];
      float4 wa=*(const float4*)wp;
      float4 wb=*(const float4*)(wp+4);
      acc[0][0]=__builtin_fmaf(x0,wa.x,acc[0][0]);
      acc[0][1]=__builtin_fmaf(x0,wa.y,acc[0][1]);
      acc[0][2]=__builtin_fmaf(x0,wa.z,acc[0][2]);
      acc[0][3]=__builtin_fmaf(x0,wa.w,acc[0][3]);
      acc[0][4]=__builtin_fmaf(x0,wb.x,acc[0][4]);
      acc[0][5]=__builtin_fmaf(x0,wb.y,acc[0][5]);
      acc[0][6]=__builtin_fmaf(x0,wb.z,acc[0][6]);
      acc[0][7]=__builtin_fmaf(x0,wb.w,acc[0][7]);
      acc[1][0]=__builtin_fmaf(x1,wa.x,acc[1][0]);
      acc[1][1]=__builtin_fmaf(x1,wa.y,acc[1][1]);
      acc[1][2]=__builtin_fmaf(x1,wa.z,acc[1][2]);
      acc[1][3]=__builtin_fmaf(x1,wa.w,acc[1][3]);
      acc[1][4]=__builtin_fmaf(x1,wb.x,acc[1][4]);
      acc[1][5]=__builtin_fmaf(x1,wb.y,acc[1][5]);
      acc[1][6]=__builtin_fmaf(x1,wb.z,acc[1][6]);
      acc[1][7]=__builtin_fmaf(x1,wb.w,acc[1][7]);
    }
    __syncthreads();
  }
#pragma unroll
  for (int a=0;a<2;a++){
    int glc=gsub*2+a;
#pragma unroll
    for (int j=0;j<8;j++){
      float bv=b1[h0+j];
      Hs[glc][h0+j]=fmaxf(__fadd_rn(acc[a][j],bv),0.f);
    }
  }
  __syncthreads();
  const int o0=h0;
#pragma unroll
  for (int j=0;j<8;j++){
    const float* wr=Wout + (size_t)(o0+j)*H_;
    float s0=0.f, s1=0.f;
#pragma unroll 8
    for (int h=0;h<H_;h++){
      float w=wr[h];
      s0=__builtin_fmaf(Hs[2*gsub][h],  w, s0);
      s1=__builtin_fmaf(Hs[2*gsub+1][h],w, s1);
    }
    float bv=bout[o0+j];
    int ga=g0+2*gsub, gb=ga+1;
    xout[(size_t)ga*256+128+o0+j]=__fadd_rn(s0,bv);
    xout[(size_t)gb*256+128+o0+j]=__fadd_rn(s1,bv);
  }
}

// ----------------------------------------------------------------
extern "C" void kernel_launch(void* const* d_in, const int* in_sizes, int n_in,
                              void* d_out, int out_size, void* d_ws, size_t ws_size,
                              hipStream_t stream) {
  const float* xyz  =(const float*)d_in[0];
  const float* feats=(const float*)d_in[1];
  const float* gW1  =(const float*)d_in[2];
  const float* gWout=(const float*)d_in[3];
  const float* fW1  =(const float*)d_in[4];
  const float* fb1  =(const float*)d_in[5];
  const float* fWout=(const float*)d_in[6];
  const float* fbout=(const float*)d_in[7];
  float* out=(float*)d_out;

  u16t* gidx16=(u16t*)d_ws;          // 1 MB
  float* xout = out + (size_t)B_*M_*3;

  fps_kernel <<<dim3(B_),          dim3(512), 0, stream>>>(xyz, out);
  knn_kernel <<<dim3((B_*M_)/4),   dim3(256), 0, stream>>>(xyz, out, gidx16);
  geo_kernel <<<dim3((B_*M_)/32),  dim3(256), 0, stream>>>(xyz, out, gidx16, gW1, gWout, xout);
  feat_kernel<<<dim3((B_*M_)/32),  dim3(256), 0, stream>>>(feats, gidx16, fW1, fb1, fWout, fbout, xout);
}

// Round 5
// 1397.736 us; speedup vs baseline: 2.1791x; 1.2980x over previous
//
#include <hip/hip_runtime.h>
#include <float.h>

#define B_ 16
#define N_ 4096
#define M_ 1024
#define K_ 32
#define FEAT_ 64
#define H_ 128
#define GEO_IN_ 160
#define GEO_MID_ 130
#define FEAT_IN_ 2048

typedef unsigned short u16t;

// ---- wave64 reductions in the VALU pipe (DPP), identity-preserving ----
// row_shr:N = 0x110+N, row_bcast15 = 0x142, row_bcast31 = 0x143.
// old=v (bound_ctrl=false) => invalid lanes keep own value (identity).
#define DPP_STEP_MAX(ctrl) \
  t=(unsigned)__builtin_amdgcn_update_dpp((int)v,(int)v,(ctrl),0xf,0xf,false); \
  v=(t>v)?t:v;
#define DPP_STEP_MIN(ctrl) \
  t=(unsigned)__builtin_amdgcn_update_dpp((int)v,(int)v,(ctrl),0xf,0xf,false); \
  v=(t<v)?t:v;

__device__ __forceinline__ unsigned wave_max_u32(unsigned v){
  unsigned t;
  DPP_STEP_MAX(0x111) DPP_STEP_MAX(0x112) DPP_STEP_MAX(0x114) DPP_STEP_MAX(0x118)
  DPP_STEP_MAX(0x142) DPP_STEP_MAX(0x143)
  return (unsigned)__builtin_amdgcn_readlane((int)v,63);
}
__device__ __forceinline__ unsigned wave_min_u32(unsigned v){
  unsigned t;
  DPP_STEP_MIN(0x111) DPP_STEP_MIN(0x112) DPP_STEP_MIN(0x114) DPP_STEP_MIN(0x118)
  DPP_STEP_MIN(0x142) DPP_STEP_MIN(0x143)
  return (unsigned)__builtin_amdgcn_readlane((int)v,63);
}

// ---------------------------------------------------------------- FPS
// One block (512 thr = 8 waves) per batch. 8 pts/thread in registers; full
// point cloud mirrored in LDS (48KB) for broadcast winner-coord fetch.
// Per step: local argmax -> 2x DPP wave reduction (VALU pipe) -> 1 barrier
// (ping-pong key buffer) -> u64 scan of 8 wave keys -> LDS coord read.
// Semantics: max dist, tie -> smallest index; no FMA contraction in distance.
__global__ __launch_bounds__(512) void fps_kernel(
    const float* __restrict__ xyz, float* __restrict__ outc)
{
  const int b = blockIdx.x, tid = threadIdx.x;
  const int lane = tid & 63, wv = tid >> 6;
  const float* xb = xyz + (size_t)b * (N_*3);
  __shared__ float spt[N_*3];
  __shared__ __align__(16) unsigned long long kw[2][8];
  for (int e=tid; e<N_*3; e+=512) spt[e]=xb[e];
  float px[8], py[8], pz[8], dd[8];
#pragma unroll
  for (int j=0;j<8;j++){
    int i = tid + 512*j;
    px[j]=xb[i*3]; py[j]=xb[i*3+1]; pz[j]=xb[i*3+2];
    dd[j]=FLT_MAX;
  }
  float lx=xb[0], ly=xb[1], lz=xb[2];
  if (tid==0){
    size_t cb=(size_t)b*M_*3;
    outc[cb]=lx; outc[cb+1]=ly; outc[cb+2]=lz;
  }
  __syncthreads();
  for (int t=1;t<M_;t++){
    float bd=-FLT_MAX; int bi=0;
#pragma unroll
    for (int j=0;j<8;j++){
      float dx=__fsub_rn(px[j],lx), dy=__fsub_rn(py[j],ly), dz=__fsub_rn(pz[j],lz);
      float d=__fadd_rn(__fadd_rn(__fmul_rn(dx,dx),__fmul_rn(dy,dy)),__fmul_rn(dz,dz));
      d=fminf(dd[j],d); dd[j]=d;
      if (d>bd){ bd=d; bi=tid+512*j; }   // j asc => idx asc; strict > keeps first max
    }
    // bd >= 0 => raw IEEE bits are order-monotone for u32 compare
    unsigned db=__float_as_uint(bd);
    unsigned smax=wave_max_u32(db);
    unsigned cand=(db==smax)?(unsigned)bi:0x7FFFFFFFu;
    unsigned sbi=wave_min_u32(cand);
    if (lane==0) kw[t&1][wv]=((unsigned long long)smax<<32)|(unsigned)(0xFFFFFFFFu-sbi);
    __syncthreads();
    const unsigned long long* kp=kw[t&1];
    unsigned long long wk=kp[0];
#pragma unroll
    for (int w=1;w<8;w++){ unsigned long long o=kp[w]; if (o>wk) wk=o; }
    int ci=(int)(0xFFFFFFFFu-(unsigned)wk);
    lx=spt[3*ci]; ly=spt[3*ci+1]; lz=spt[3*ci+2];
    if (tid==0){
      size_t cb=((size_t)b*M_+(size_t)t)*3;
      outc[cb]=lx; outc[cb+1]=ly; outc[cb+2]=lz;
    }
  }
}

// ---------------------------------------------------------------- KNN
// One wave per centroid. 64 dists/lane in registers. 32 selection iterations,
// each: 2x DPP wave reduction (min orderable-dist, then min idx among ties)
// == stable top_k (tie -> smallest index). Owner lane rescans its 64 slots.
__global__ __launch_bounds__(256) void knn_kernel(
    const float* __restrict__ xyz, const float* __restrict__ outc,
    u16t* __restrict__ gidx16)
{
  const int w = blockIdx.x*4 + (threadIdx.x>>6);
  const int lane = threadIdx.x & 63;
  const int b = w >> 10;
  const float* xb = xyz + (size_t)b*(N_*3);
  float cx=outc[(size_t)w*3], cy=outc[(size_t)w*3+1], cz=outc[(size_t)w*3+2];
  float c2=__fadd_rn(__fadd_rn(__fmul_rn(cx,cx),__fmul_rn(cy,cy)),__fmul_rn(cz,cz));
  float dl[64];
  float lv=FLT_MAX; int lj=0;
#pragma unroll
  for (int j=0;j<64;j++){
    int i = lane + 64*j;
    float xx=xb[i*3], xy=xb[i*3+1], xz=xb[i*3+2];
    float x2=__fadd_rn(__fadd_rn(__fmul_rn(xx,xx),__fmul_rn(xy,xy)),__fmul_rn(xz,xz));
    float dt=__fadd_rn(__fadd_rn(__fmul_rn(cx,xx),__fmul_rn(cy,xy)),__fmul_rn(cz,xz));
    float d=__fsub_rn(__fadd_rn(c2,x2),__fmul_rn(2.f,dt));
    dl[j]=d;
    if (d<lv){ lv=d; lj=j; }
  }
  const int wb = w*K_;
  for (int k=0;k<K_;k++){
    unsigned u=__float_as_uint(lv);
    u = (u&0x80000000u) ? ~u : (u|0x80000000u);   // order-preserving (d may round <0)
    unsigned smin=wave_min_u32(u);
    unsigned cand=(u==smin)?(unsigned)(lane+64*lj):0xFFFFFFFFu;
    unsigned widx=wave_min_u32(cand);
    if (lane==0) gidx16[wb+k]=(u16t)widx;
    if ((widx & 63)==(unsigned)lane){
      int slot=(int)(widx>>6);
      float nv=FLT_MAX; int nj=0;
#pragma unroll
      for (int j=0;j<64;j++){
        float v=(j==slot)?FLT_MAX:dl[j];
        dl[j]=v;
        if (v<nv){ nv=v; nj=j; }
      }
      lv=nv; lj=nj;
    }
  }
}

// ---------------------------------------------------------------- GEO fused (GEMM-style)
// (unchanged from round 4)
__global__ __launch_bounds__(256) void geo_kernel(
    const float* __restrict__ xyz, const float* __restrict__ outc,
    const u16t* __restrict__ gidx16, const float* __restrict__ W1,
    const float* __restrict__ Wout, float* __restrict__ xout)
{
  __shared__ float smem[160*33 + 64*128 + 32];
  float (*Es)[33]  = (float(*)[33])smem;
  float (*Hs)[33]  = (float(*)[33])smem;
  float (*Ws)[128] = (float(*)[128])(smem + 160*33);
  float* ssv = smem + 160*33 + 64*128;

  const int t=threadIdx.x;
  const int g0=blockIdx.x*32;
  for (int p=t; p<1024; p+=256){
    int g=p>>5, kk=p&31;
    int gg=g0+g, b=gg>>10;
    int idx=gidx16[gg*K_+kk];
    const float* pt = xyz + ((size_t)b*N_+(size_t)idx)*3;
    const float* cc = outc + (size_t)gg*3;
    float dx=__fsub_rn(pt[0],cc[0]);
    float dy=__fsub_rn(pt[1],cc[1]);
    float dz=__fsub_rn(pt[2],cc[2]);
    float sq=__fadd_rn(__fadd_rn(__fmul_rn(dx,dx),__fmul_rn(dy,dy)),__fmul_rn(dz,dz));
    int r=5*kk;
    Es[r][g]=dx; Es[r+1][g]=dy; Es[r+2][g]=dz;
    Es[r+3][g]=-1.f; Es[r+4][g]=__fmul_rn(-0.5f,sq);
  }
  const int gsub=t>>4, hsub=t&15, h0=hsub*8;
  const int hw=t>>1;
  float acc[2][8];
#pragma unroll
  for (int a=0;a<2;a++)
#pragma unroll
    for (int j=0;j<8;j++) acc[a][j]=0.f;
  __syncthreads();

  for (int c=0;c<3;c++){
    int i0=c*64;
    if (c<2){
      int fw0=(t&1)*32;
      const float* wr = W1 + (size_t)hw*GEO_IN_ + i0 + fw0;
      float4 wv[8];
#pragma unroll
      for (int e=0;e<8;e++) wv[e]=((const float4*)wr)[e];
#pragma unroll
      for (int e=0;e<8;e++){
        Ws[fw0+4*e+0][hw]=wv[e].x;
        Ws[fw0+4*e+1][hw]=wv[e].y;
        Ws[fw0+4*e+2][hw]=wv[e].z;
        Ws[fw0+4*e+3][hw]=wv[e].w;
      }
    } else {
      int fw0=(t&1)*16;
      const float* wr = W1 + (size_t)hw*GEO_IN_ + 128 + fw0;
      float4 wv[4];
#pragma unroll
      for (int e=0;e<4;e++) wv[e]=((const float4*)wr)[e];
#pragma unroll
      for (int e=0;e<4;e++){
        Ws[fw0+4*e+0][hw]=wv[e].x;
        Ws[fw0+4*e+1][hw]=wv[e].y;
        Ws[fw0+4*e+2][hw]=wv[e].z;
        Ws[fw0+4*e+3][hw]=wv[e].w;
      }
    }
    __syncthreads();
    int len=(c==2)?32:64;
    for (int k2=0;k2<len;k2++){
      float x0=Es[i0+k2][2*gsub], x1=Es[i0+k2][2*gsub+1];
      const float* wp=&Ws[k2][h0];
      float4 wa=*(const float4*)wp;
      float4 wb=*(const float4*)(wp+4);
      acc[0][0]=__builtin_fmaf(x0,wa.x,acc[0][0]);
      acc[0][1]=__builtin_fmaf(x0,wa.y,acc[0][1]);
      acc[0][2]=__builtin_fmaf(x0,wa.z,acc[0][2]);
      acc[0][3]=__builtin_fmaf(x0,wa.w,acc[0][3]);
      acc[0][4]=__builtin_fmaf(x0,wb.x,acc[0][4]);
      acc[0][5]=__builtin_fmaf(x0,wb.y,acc[0][5]);
      acc[0][6]=__builtin_fmaf(x0,wb.z,acc[0][6]);
      acc[0][7]=__builtin_fmaf(x0,wb.w,acc[0][7]);
      acc[1][0]=__builtin_fmaf(x1,wa.x,acc[1][0]);
      acc[1][1]=__builtin_fmaf(x1,wa.y,acc[1][1]);
      acc[1][2]=__builtin_fmaf(x1,wa.z,acc[1][2]);
      acc[1][3]=__builtin_fmaf(x1,wa.w,acc[1][3]);
      acc[1][4]=__builtin_fmaf(x1,wb.x,acc[1][4]);
      acc[1][5]=__builtin_fmaf(x1,wb.y,acc[1][5]);
      acc[1][6]=__builtin_fmaf(x1,wb.z,acc[1][6]);
      acc[1][7]=__builtin_fmaf(x1,wb.w,acc[1][7]);
    }
    __syncthreads();
  }
#pragma unroll
  for (int a=0;a<2;a++)
#pragma unroll
    for (int j=0;j<8;j++)
      Hs[h0+j][2*gsub+a]=acc[a][j];
  __syncthreads();
  if (t<32){
    float ss=0.f;
    for (int h=0;h<H_;h++){ float v=Hs[h][t]; ss=__builtin_fmaf(v,v,ss); }
    ssv[t]=__fmul_rn(-0.5f,ss);
  }
#pragma unroll
  for (int a=0;a<2;a++)
#pragma unroll
    for (int j=0;j<8;j++) acc[a][j]=0.f;
  for (int c=0;c<2;c++){
    int i0=c*64;
    int fw0=(t&1)*32;
    const float* wr = Wout + (size_t)hw*GEO_MID_ + i0 + fw0;
    float2 wv2[16];
#pragma unroll
    for (int e=0;e<16;e++) wv2[e]=((const float2*)wr)[e];
    __syncthreads();
#pragma unroll
    for (int e=0;e<16;e++){
      Ws[fw0+2*e+0][hw]=wv2[e].x;
      Ws[fw0+2*e+1][hw]=wv2[e].y;
    }
    __syncthreads();
    for (int k2=0;k2<64;k2++){
      float x0=Hs[i0+k2][2*gsub], x1=Hs[i0+k2][2*gsub+1];
      const float* wp=&Ws[k2][h0];
      float4 wa=*(const float4*)wp;
      float4 wb=*(const float4*)(wp+4);
      acc[0][0]=__builtin_fmaf(x0,wa.x,acc[0][0]);
      acc[0][1]=__builtin_fmaf(x0,wa.y,acc[0][1]);
      acc[0][2]=__builtin_fmaf(x0,wa.z,acc[0][2]);
      acc[0][3]=__builtin_fmaf(x0,wa.w,acc[0][3]);
      acc[0][4]=__builtin_fmaf(x0,wb.x,acc[0][4]);
      acc[0][5]=__builtin_fmaf(x0,wb.y,acc[0][5]);
      acc[0][6]=__builtin_fmaf(x0,wb.z,acc[0][6]);
      acc[0][7]=__builtin_fmaf(x0,wb.w,acc[0][7]);
      acc[1][0]=__builtin_fmaf(x1,wa.x,acc[1][0]);
      acc[1][1]=__builtin_fmaf(x1,wa.y,acc[1][1]);
      acc[1][2]=__builtin_fmaf(x1,wa.z,acc[1][2]);
      acc[1][3]=__builtin_fmaf(x1,wa.w,acc[1][3]);
      acc[1][4]=__builtin_fmaf(x1,wb.x,acc[1][4]);
      acc[1][5]=__builtin_fmaf(x1,wb.y,acc[1][5]);
      acc[1][6]=__builtin_fmaf(x1,wb.z,acc[1][6]);
      acc[1][7]=__builtin_fmaf(x1,wb.w,acc[1][7]);
    }
  }
#pragma unroll
  for (int j=0;j<8;j++){
    int o=h0+j;
    float2 we=*(const float2*)(Wout + (size_t)o*GEO_MID_ + 128);
#pragma unroll
    for (int a=0;a<2;a++){
      float v=acc[a][j];
      v=__builtin_fmaf(-1.f, we.x, v);
      v=__builtin_fmaf(ssv[2*gsub+a], we.y, v);
      xout[(size_t)(g0+2*gsub+a)*256 + o]=v;
    }
  }
}

// ---------------------------------------------------------------- FEAT fused
// (unchanged from round 4)
__global__ __launch_bounds__(256) void feat_kernel(
    const float* __restrict__ feats, const u16t* __restrict__ gidx16,
    const float* __restrict__ W1, const float* __restrict__ b1,
    const float* __restrict__ Wout, const float* __restrict__ bout,
    float* __restrict__ xout)
{
  __shared__ float Xs[64][33];
  __shared__ float Ws[64][128];
  __shared__ float Hs[32][129];
  const int t=threadIdx.x;
  const int g0=blockIdx.x*32;
  const int gsub=t>>4, hsub=t&15, h0=hsub*8;
  const int gl=t>>3, f0=(t&7)*8;
  const int gld=g0+gl, bld=gld>>10;
  const int hw=t>>1, fw0=(t&1)*32;
  float acc[2][8];
#pragma unroll
  for (int a=0;a<2;a++)
#pragma unroll
    for (int j=0;j<8;j++) acc[a][j]=0.f;

  for (int kk=0;kk<K_;kk++){
    int nidx=gidx16[gld*K_+kk];
    const float* fr=feats + ((size_t)bld*N_+(size_t)nidx)*FEAT_ + f0;
    float4 p0=((const float4*)fr)[0];
    float4 p1=((const float4*)fr)[1];
    const float* wr=W1 + (size_t)hw*FEAT_IN_ + kk*64 + fw0;
    float4 wv[8];
#pragma unroll
    for (int e=0;e<8;e++) wv[e]=((const float4*)wr)[e];
    Xs[f0+0][gl]=p0.x; Xs[f0+1][gl]=p0.y; Xs[f0+2][gl]=p0.z; Xs[f0+3][gl]=p0.w;
    Xs[f0+4][gl]=p1.x; Xs[f0+5][gl]=p1.y; Xs[f0+6][gl]=p1.z; Xs[f0+7][gl]=p1.w;
#pragma unroll
    for (int e=0;e<8;e++){
      Ws[fw0+4*e+0][hw]=wv[e].x;
      Ws[fw0+4*e+1][hw]=wv[e].y;
      Ws[fw0+4*e+2][hw]=wv[e].z;
      Ws[fw0+4*e+3][hw]=wv[e].w;
    }
    __syncthreads();
#pragma unroll 8
    for (int k2=0;k2<64;k2++){
      float x0=Xs[k2][2*gsub], x1=Xs[k2][2*gsub+1];
      const float* wp=&Ws[k2][h0];
      float4 wa=*(const float4*)wp;
      float4 wb=*(const float4*)(wp+4);
      acc[0][0]=__builtin_fmaf(x0,wa.x,acc[0][0]);
      acc[0][1]=__builtin_fmaf(x0,wa.y,acc[0][1]);
      acc[0][2]=__builtin_fmaf(x0,wa.z,acc[0][2]);
      acc[0][3]=__builtin_fmaf(x0,wa.w,acc[0][3]);
      acc[0][4]=__builtin_fmaf(x0,wb.x,acc[0][4]);
      acc[0][5]=__builtin_fmaf(x0,wb.y,acc[0][5]);
      acc[0][6]=__builtin_fmaf(x0,wb.z,acc[0][6]);
      acc[0][7]=__builtin_fmaf(x0,wb.w,acc[0][7]);
      acc[1][0]=__builtin_fmaf(x1,wa.x,acc[1][0]);
      acc[1][1]=__builtin_fmaf(x1,wa.y,acc[1][1]);
      acc[1][2]=__builtin_fmaf(x1,wa.z,acc[1][2]);
      acc[1][3]=__builtin_fmaf(x1,wa.w,acc[1][3]);
      acc[1][4]=__builtin_fmaf(x1,wb.x,acc[1][4]);
      acc[1][5]=__builtin_fmaf(x1,wb.y,acc[1][5]);
      acc[1][6]=__builtin_fmaf(x1,wb.z,acc[1][6]);
      acc[1][7]=__builtin_fmaf(x1,wb.w,acc[1][7]);
    }
    __syncthreads();
  }
#pragma unroll
  for (int a=0;a<2;a++){
    int glc=gsub*2+a;
#pragma unroll
    for (int j=0;j<8;j++){
      float bv=b1[h0+j];
      Hs[glc][h0+j]=fmaxf(__fadd_rn(acc[a][j],bv),0.f);
    }
  }
  __syncthreads();
  const int o0=h0;
#pragma unroll
  for (int j=0;j<8;j++){
    const float* wr=Wout + (size_t)(o0+j)*H_;
    float s0=0.f, s1=0.f;
#pragma unroll 8
    for (int h=0;h<H_;h++){
      float w=wr[h];
      s0=__builtin_fmaf(Hs[2*gsub][h],  w, s0);
      s1=__builtin_fmaf(Hs[2*gsub+1][h],w, s1);
    }
    float bv=bout[o0+j];
    int ga=g0+2*gsub, gb=ga+1;
    xout[(size_t)ga*256+128+o0+j]=__fadd_rn(s0,bv);
    xout[(size_t)gb*256+128+o0+j]=__fadd_rn(s1,bv);
  }
}

// ----------------------------------------------------------------
extern "C" void kernel_launch(void* const* d_in, const int* in_sizes, int n_in,
                              void* d_out, int out_size, void* d_ws, size_t ws_size,
                              hipStream_t stream) {
  const float* xyz  =(const float*)d_in[0];
  const float* feats=(const float*)d_in[1];
  const float* gW1  =(const float*)d_in[2];
  const float* gWout=(const float*)d_in[3];
  const float* fW1  =(const float*)d_in[4];
  const float* fb1  =(const float*)d_in[5];
  const float* fWout=(const float*)d_in[6];
  const float* fbout=(const float*)d_in[7];
  float* out=(float*)d_out;

  u16t* gidx16=(u16t*)d_ws;          // 1 MB
  float* xout = out + (size_t)B_*M_*3;

  fps_kernel <<<dim3(B_),          dim3(512), 0, stream>>>(xyz, out);
  knn_kernel <<<dim3((B_*M_)/4),   dim3(256), 0, stream>>>(xyz, out, gidx16);
  geo_kernel <<<dim3((B_*M_)/32),  dim3(256), 0, stream>>>(xyz, out, gidx16, gW1, gWout, xout);
  feat_kernel<<<dim3((B_*M_)/32),  dim3(256), 0, stream>>>(feats, gidx16, fW1, fb1, fWout, fbout, xout);
}

// Round 6
// 1331.930 us; speedup vs baseline: 2.2868x; 1.0494x over previous
//
#include <hip/hip_runtime.h>
#include <float.h>

#define B_ 16
#define N_ 4096
#define M_ 1024
#define K_ 32
#define FEAT_ 64
#define H_ 128
#define GEO_IN_ 160
#define GEO_MID_ 130
#define FEAT_IN_ 2048

typedef unsigned short u16t;

// ---- wave64 reductions in the VALU pipe (DPP), identity-preserving ----
#define DPP_STEP_MAX(ctrl) \
  t=(unsigned)__builtin_amdgcn_update_dpp((int)v,(int)v,(ctrl),0xf,0xf,false); \
  v=(t>v)?t:v;
#define DPP_STEP_MIN(ctrl) \
  t=(unsigned)__builtin_amdgcn_update_dpp((int)v,(int)v,(ctrl),0xf,0xf,false); \
  v=(t<v)?t:v;

__device__ __forceinline__ unsigned wave_max_u32(unsigned v){
  unsigned t;
  DPP_STEP_MAX(0x111) DPP_STEP_MAX(0x112) DPP_STEP_MAX(0x114) DPP_STEP_MAX(0x118)
  DPP_STEP_MAX(0x142) DPP_STEP_MAX(0x143)
  return (unsigned)__builtin_amdgcn_readlane((int)v,63);
}
__device__ __forceinline__ unsigned wave_min_u32(unsigned v){
  unsigned t;
  DPP_STEP_MIN(0x111) DPP_STEP_MIN(0x112) DPP_STEP_MIN(0x114) DPP_STEP_MIN(0x118)
  DPP_STEP_MIN(0x142) DPP_STEP_MIN(0x143)
  return (unsigned)__builtin_amdgcn_readlane((int)v,63);
}

// ---------------------------------------------------------------- FPS
// One block (512 thr = 8 waves) per batch. NO global memory ops inside the
// step loop: winner indices recorded in LDS (cis), centroids bulk-written at
// the end from the LDS point mirror. Barrier drains only LDS traffic.
// Semantics: max dist, tie -> smallest index; no FMA contraction in distance.
__global__ __launch_bounds__(512) void fps_kernel(
    const float* __restrict__ xyz, float* __restrict__ outc)
{
  const int b = blockIdx.x, tid = threadIdx.x;
  const int lane = tid & 63, wv = tid >> 6;
  const float* xb = xyz + (size_t)b * (N_*3);
  __shared__ float spt[N_*3];
  __shared__ __align__(16) unsigned long long kw[2][8];
  __shared__ int cis[M_];
  for (int v=tid; v<(N_*3)/4; v+=512)
    ((float4*)spt)[v]=((const float4*)xb)[v];
  float px[8], py[8], pz[8], dd[8];
#pragma unroll
  for (int j=0;j<8;j++){
    int i = tid + 512*j;
    px[j]=xb[i*3]; py[j]=xb[i*3+1]; pz[j]=xb[i*3+2];
    dd[j]=FLT_MAX;
  }
  float lx=xb[0], ly=xb[1], lz=xb[2];
  if (tid==0) cis[0]=0;
  __syncthreads();
  for (int t=1;t<M_;t++){
    float bd=-FLT_MAX; int bi=0;
#pragma unroll
    for (int j=0;j<8;j++){
      float dx=__fsub_rn(px[j],lx), dy=__fsub_rn(py[j],ly), dz=__fsub_rn(pz[j],lz);
      float d=__fadd_rn(__fadd_rn(__fmul_rn(dx,dx),__fmul_rn(dy,dy)),__fmul_rn(dz,dz));
      d=fminf(dd[j],d); dd[j]=d;
      if (d>bd){ bd=d; bi=tid+512*j; }   // j asc => idx asc; strict > keeps first max
    }
    unsigned db=__float_as_uint(bd);          // bd>=0 => raw bits order-monotone
    unsigned smax=wave_max_u32(db);
    unsigned cand=(db==smax)?(unsigned)bi:0x7FFFFFFFu;
    unsigned sbi=wave_min_u32(cand);
    if (lane==0) kw[t&1][wv]=((unsigned long long)smax<<32)|(unsigned)(0xFFFFFFFFu-sbi);
    __syncthreads();
    const unsigned long long* kp=kw[t&1];
    unsigned long long wk=kp[0];
#pragma unroll
    for (int w=1;w<8;w++){ unsigned long long o=kp[w]; if (o>wk) wk=o; }
    int ci=(int)(0xFFFFFFFFu-(unsigned)wk);
    if (tid==0) cis[t]=ci;
    lx=spt[3*ci]; ly=spt[3*ci+1]; lz=spt[3*ci+2];
  }
  __syncthreads();
  // bulk centroid write (one global pass, off the critical loop)
  for (int e=tid; e<M_; e+=512){
    int ci=cis[e];
    size_t cb=((size_t)b*M_+(size_t)e)*3;
    outc[cb]=spt[3*ci]; outc[cb+1]=spt[3*ci+1]; outc[cb+2]=spt[3*ci+2];
  }
}

// ---------------------------------------------------------------- KNN
// (unchanged from round 5 — bit-identical selection)
__global__ __launch_bounds__(256) void knn_kernel(
    const float* __restrict__ xyz, const float* __restrict__ outc,
    u16t* __restrict__ gidx16)
{
  const int w = blockIdx.x*4 + (threadIdx.x>>6);
  const int lane = threadIdx.x & 63;
  const int b = w >> 10;
  const float* xb = xyz + (size_t)b*(N_*3);
  float cx=outc[(size_t)w*3], cy=outc[(size_t)w*3+1], cz=outc[(size_t)w*3+2];
  float c2=__fadd_rn(__fadd_rn(__fmul_rn(cx,cx),__fmul_rn(cy,cy)),__fmul_rn(cz,cz));
  float dl[64];
  float lv=FLT_MAX; int lj=0;
#pragma unroll
  for (int j=0;j<64;j++){
    int i = lane + 64*j;
    float xx=xb[i*3], xy=xb[i*3+1], xz=xb[i*3+2];
    float x2=__fadd_rn(__fadd_rn(__fmul_rn(xx,xx),__fmul_rn(xy,xy)),__fmul_rn(xz,xz));
    float dt=__fadd_rn(__fadd_rn(__fmul_rn(cx,xx),__fmul_rn(cy,xy)),__fmul_rn(cz,xz));
    float d=__fsub_rn(__fadd_rn(c2,x2),__fmul_rn(2.f,dt));
    dl[j]=d;
    if (d<lv){ lv=d; lj=j; }
  }
  const int wb = w*K_;
  for (int k=0;k<K_;k++){
    unsigned u=__float_as_uint(lv);
    u = (u&0x80000000u) ? ~u : (u|0x80000000u);   // order-preserving
    unsigned smin=wave_min_u32(u);
    unsigned cand=(u==smin)?(unsigned)(lane+64*lj):0xFFFFFFFFu;
    unsigned widx=wave_min_u32(cand);
    if (lane==0) gidx16[wb+k]=(u16t)widx;
    if ((widx & 63)==(unsigned)lane){
      int slot=(int)(widx>>6);
      float nv=FLT_MAX; int nj=0;
#pragma unroll
      for (int j=0;j<64;j++){
        float v=(j==slot)?FLT_MAX:dl[j];
        dl[j]=v;
        if (v<nv){ nv=v; nj=j; }
      }
      lv=nv; lj=nj;
    }
  }
}

// ---------------------------------------------------------------- GEO fused (GEMM-style)
// (unchanged from round 5)
__global__ __launch_bounds__(256) void geo_kernel(
    const float* __restrict__ xyz, const float* __restrict__ outc,
    const u16t* __restrict__ gidx16, const float* __restrict__ W1,
    const float* __restrict__ Wout, float* __restrict__ xout)
{
  __shared__ float smem[160*33 + 64*128 + 32];
  float (*Es)[33]  = (float(*)[33])smem;
  float (*Hs)[33]  = (float(*)[33])smem;
  float (*Ws)[128] = (float(*)[128])(smem + 160*33);
  float* ssv = smem + 160*33 + 64*128;

  const int t=threadIdx.x;
  const int g0=blockIdx.x*32;
  for (int p=t; p<1024; p+=256){
    int g=p>>5, kk=p&31;
    int gg=g0+g, b=gg>>10;
    int idx=gidx16[gg*K_+kk];
    const float* pt = xyz + ((size_t)b*N_+(size_t)idx)*3;
    const float* cc = outc + (size_t)gg*3;
    float dx=__fsub_rn(pt[0],cc[0]);
    float dy=__fsub_rn(pt[1],cc[1]);
    float dz=__fsub_rn(pt[2],cc[2]);
    float sq=__fadd_rn(__fadd_rn(__fmul_rn(dx,dx),__fmul_rn(dy,dy)),__fmul_rn(dz,dz));
    int r=5*kk;
    Es[r][g]=dx; Es[r+1][g]=dy; Es[r+2][g]=dz;
    Es[r+3][g]=-1.f; Es[r+4][g]=__fmul_rn(-0.5f,sq);
  }
  const int gsub=t>>4, hsub=t&15, h0=hsub*8;
  const int hw=t>>1;
  float acc[2][8];
#pragma unroll
  for (int a=0;a<2;a++)
#pragma unroll
    for (int j=0;j<8;j++) acc[a][j]=0.f;
  __syncthreads();

  for (int c=0;c<3;c++){
    int i0=c*64;
    if (c<2){
      int fw0=(t&1)*32;
      const float* wr = W1 + (size_t)hw*GEO_IN_ + i0 + fw0;
      float4 wv[8];
#pragma unroll
      for (int e=0;e<8;e++) wv[e]=((const float4*)wr)[e];
#pragma unroll
      for (int e=0;e<8;e++){
        Ws[fw0+4*e+0][hw]=wv[e].x;
        Ws[fw0+4*e+1][hw]=wv[e].y;
        Ws[fw0+4*e+2][hw]=wv[e].z;
        Ws[fw0+4*e+3][hw]=wv[e].w;
      }
    } else {
      int fw0=(t&1)*16;
      const float* wr = W1 + (size_t)hw*GEO_IN_ + 128 + fw0;
      float4 wv[4];
#pragma unroll
      for (int e=0;e<4;e++) wv[e]=((const float4*)wr)[e];
#pragma unroll
      for (int e=0;e<4;e++){
        Ws[fw0+4*e+0][hw]=wv[e].x;
        Ws[fw0+4*e+1][hw]=wv[e].y;
        Ws[fw0+4*e+2][hw]=wv[e].z;
        Ws[fw0+4*e+3][hw]=wv[e].w;
      }
    }
    __syncthreads();
    int len=(c==2)?32:64;
    for (int k2=0;k2<len;k2++){
      float x0=Es[i0+k2][2*gsub], x1=Es[i0+k2][2*gsub+1];
      const float* wp=&Ws[k2][h0];
      float4 wa=*(const float4*)wp;
      float4 wb=*(const float4*)(wp+4);
      acc[0][0]=__builtin_fmaf(x0,wa.x,acc[0][0]);
      acc[0][1]=__builtin_fmaf(x0,wa.y,acc[0][1]);
      acc[0][2]=__builtin_fmaf(x0,wa.z,acc[0][2]);
      acc[0][3]=__builtin_fmaf(x0,wa.w,acc[0][3]);
      acc[0][4]=__builtin_fmaf(x0,wb.x,acc[0][4]);
      acc[0][5]=__builtin_fmaf(x0,wb.y,acc[0][5]);
      acc[0][6]=__builtin_fmaf(x0,wb.z,acc[0][6]);
      acc[0][7]=__builtin_fmaf(x0,wb.w,acc[0][7]);
      acc[1][0]=__builtin_fmaf(x1,wa.x,acc[1][0]);
      acc[1][1]=__builtin_fmaf(x1,wa.y,acc[1][1]);
      acc[1][2]=__builtin_fmaf(x1,wa.z,acc[1][2]);
      acc[1][3]=__builtin_fmaf(x1,wa.w,acc[1][3]);
      acc[1][4]=__builtin_fmaf(x1,wb.x,acc[1][4]);
      acc[1][5]=__builtin_fmaf(x1,wb.y,acc[1][5]);
      acc[1][6]=__builtin_fmaf(x1,wb.z,acc[1][6]);
      acc[1][7]=__builtin_fmaf(x1,wb.w,acc[1][7]);
    }
    __syncthreads();
  }
#pragma unroll
  for (int a=0;a<2;a++)
#pragma unroll
    for (int j=0;j<8;j++)
      Hs[h0+j][2*gsub+a]=acc[a][j];
  __syncthreads();
  if (t<32){
    float ss=0.f;
    for (int h=0;h<H_;h++){ float v=Hs[h][t]; ss=__builtin_fmaf(v,v,ss); }
    ssv[t]=__fmul_rn(-0.5f,ss);
  }
#pragma unroll
  for (int a=0;a<2;a++)
#pragma unroll
    for (int j=0;j<8;j++) acc[a][j]=0.f;
  for (int c=0;c<2;c++){
    int i0=c*64;
    int fw0=(t&1)*32;
    const float* wr = Wout + (size_t)hw*GEO_MID_ + i0 + fw0;
    float2 wv2[16];
#pragma unroll
    for (int e=0;e<16;e++) wv2[e]=((const float2*)wr)[e];
    __syncthreads();
#pragma unroll
    for (int e=0;e<16;e++){
      Ws[fw0+2*e+0][hw]=wv2[e].x;
      Ws[fw0+2*e+1][hw]=wv2[e].y;
    }
    __syncthreads();
    for (int k2=0;k2<64;k2++){
      float x0=Hs[i0+k2][2*gsub], x1=Hs[i0+k2][2*gsub+1];
      const float* wp=&Ws[k2][h0];
      float4 wa=*(const float4*)wp;
      float4 wb=*(const float4*)(wp+4);
      acc[0][0]=__builtin_fmaf(x0,wa.x,acc[0][0]);
      acc[0][1]=__builtin_fmaf(x0,wa.y,acc[0][1]);
      acc[0][2]=__builtin_fmaf(x0,wa.z,acc[0][2]);
      acc[0][3]=__builtin_fmaf(x0,wa.w,acc[0][3]);
      acc[0][4]=__builtin_fmaf(x0,wb.x,acc[0][4]);
      acc[0][5]=__builtin_fmaf(x0,wb.y,acc[0][5]);
      acc[0][6]=__builtin_fmaf(x0,wb.z,acc[0][6]);
      acc[0][7]=__builtin_fmaf(x0,wb.w,acc[0][7]);
      acc[1][0]=__builtin_fmaf(x1,wa.x,acc[1][0]);
      acc[1][1]=__builtin_fmaf(x1,wa.y,acc[1][1]);
      acc[1][2]=__builtin_fmaf(x1,wa.z,acc[1][2]);
      acc[1][3]=__builtin_fmaf(x1,wa.w,acc[1][3]);
      acc[1][4]=__builtin_fmaf(x1,wb.x,acc[1][4]);
      acc[1][5]=__builtin_fmaf(x1,wb.y,acc[1][5]);
      acc[1][6]=__builtin_fmaf(x1,wb.z,acc[1][6]);
      acc[1][7]=__builtin_fmaf(x1,wb.w,acc[1][7]);
    }
  }
#pragma unroll
  for (int j=0;j<8;j++){
    int o=h0+j;
    float2 we=*(const float2*)(Wout + (size_t)o*GEO_MID_ + 128);
#pragma unroll
    for (int a=0;a<2;a++){
      float v=acc[a][j];
      v=__builtin_fmaf(-1.f, we.x, v);
      v=__builtin_fmaf(ssv[2*gsub+a], we.y, v);
      xout[(size_t)(g0+2*gsub+a)*256 + o]=v;
    }
  }
}

// ---------------------------------------------------------------- FEAT fused
// 64 groups x 128 h per block (256 blocks). Thread = 4 groups x 8 h (32 FMA
// per 48B LDS). Row pad 68 keeps float4 alignment for X/H fragment reads.
// Layer 2: Hs[128][68] transposed in LDS (aliased over dead Xs/Ws), Wout
// staged in 4 chunks of 32 k. Accumulation order: k ascending, h ascending
// => bit-identical to previous rounds.
__global__ __launch_bounds__(256) void feat_kernel(
    const float* __restrict__ feats, const u16t* __restrict__ gidx16,
    const float* __restrict__ W1, const float* __restrict__ b1,
    const float* __restrict__ Wout, const float* __restrict__ bout,
    float* __restrict__ xout)
{
  __shared__ float smem[12800];                      // 51.2 KB
  float (*Xs)[68]  = (float(*)[68])smem;             // [64][68]
  float (*Ws)[128] = (float(*)[128])(smem + 64*68);  // [64][128]
  float (*Hs)[68]  = (float(*)[68])smem;             // [128][68] alias (post K-loop)
  float (*WoS)[128]= (float(*)[128])(smem + 128*68); // [32][128]
  const int t=threadIdx.x;
  const int g0=blockIdx.x*64;
  const int gsub=t>>4;                 // 0..15 -> groups 4*gsub..+3
  const int h0=(t&15)*8;
  const int glx=t>>2, fq=(t&3)*16;     // X staging
  const int hw=t>>1, fw0=(t&1)*32;     // W1 staging
  const int fw1=(t&1)*16;              // Wout staging
  const int gld=g0+glx, bld=gld>>10;
  float acc[4][8];
#pragma unroll
  for (int a=0;a<4;a++)
#pragma unroll
    for (int j=0;j<8;j++) acc[a][j]=0.f;

  for (int kk=0;kk<K_;kk++){
    int nidx=gidx16[gld*K_+kk];
    const float* fr=feats + ((size_t)bld*N_+(size_t)nidx)*FEAT_ + fq;
    float4 p[4];
#pragma unroll
    for (int e=0;e<4;e++) p[e]=((const float4*)fr)[e];
    const float* wr=W1 + (size_t)hw*FEAT_IN_ + kk*64 + fw0;
    float4 wv[8];
#pragma unroll
    for (int e=0;e<8;e++) wv[e]=((const float4*)wr)[e];
#pragma unroll
    for (int e=0;e<4;e++){
      Xs[fq+4*e+0][glx]=p[e].x;
      Xs[fq+4*e+1][glx]=p[e].y;
      Xs[fq+4*e+2][glx]=p[e].z;
      Xs[fq+4*e+3][glx]=p[e].w;
    }
#pragma unroll
    for (int e=0;e<8;e++){
      Ws[fw0+4*e+0][hw]=wv[e].x;
      Ws[fw0+4*e+1][hw]=wv[e].y;
      Ws[fw0+4*e+2][hw]=wv[e].z;
      Ws[fw0+4*e+3][hw]=wv[e].w;
    }
    __syncthreads();
#pragma unroll 4
    for (int k2=0;k2<64;k2++){
      float4 xv=*(const float4*)&Xs[k2][4*gsub];
      const float* wp=&Ws[k2][h0];
      float4 wa=*(const float4*)wp;
      float4 wb=*(const float4*)(wp+4);
      float xr[4]={xv.x,xv.y,xv.z,xv.w};
      float wf[8]={wa.x,wa.y,wa.z,wa.w,wb.x,wb.y,wb.z,wb.w};
#pragma unroll
      for (int a=0;a<4;a++)
#pragma unroll
        for (int j=0;j<8;j++)
          acc[a][j]=__builtin_fmaf(xr[a],wf[j],acc[a][j]);
    }
    __syncthreads();
  }
  // bias + relu -> Hs transposed (clobbers Xs/Ws: all reads done, barrier above)
#pragma unroll
  for (int j=0;j<8;j++){
    float bv=b1[h0+j];
#pragma unroll
    for (int a=0;a<4;a++)
      Hs[h0+j][4*gsub+a]=fmaxf(__fadd_rn(acc[a][j],bv),0.f);
  }
  float ac2[4][8];
#pragma unroll
  for (int a=0;a<4;a++)
#pragma unroll
    for (int j=0;j<8;j++) ac2[a][j]=0.f;
  // layer 2: 4 chunks of 32 k
  for (int c=0;c<4;c++){
    const float* wr2=Wout + (size_t)hw*H_ + c*32 + fw1;
    float4 w2[4];
#pragma unroll
    for (int e=0;e<4;e++) w2[e]=((const float4*)wr2)[e];
    __syncthreads();   // prev chunk readers done (and Hs writes before first reads)
#pragma unroll
    for (int e=0;e<4;e++){
      WoS[fw1+4*e+0][hw]=w2[e].x;
      WoS[fw1+4*e+1][hw]=w2[e].y;
      WoS[fw1+4*e+2][hw]=w2[e].z;
      WoS[fw1+4*e+3][hw]=w2[e].w;
    }
    __syncthreads();
#pragma unroll 4
    for (int k2=0;k2<32;k2++){
      float4 xv=*(const float4*)&Hs[c*32+k2][4*gsub];
      const float* wp=&WoS[k2][h0];
      float4 wa=*(const float4*)wp;
      float4 wb=*(const float4*)(wp+4);
      float xr[4]={xv.x,xv.y,xv.z,xv.w};
      float wf[8]={wa.x,wa.y,wa.z,wa.w,wb.x,wb.y,wb.z,wb.w};
#pragma unroll
      for (int a=0;a<4;a++)
#pragma unroll
        for (int j=0;j<8;j++)
          ac2[a][j]=__builtin_fmaf(xr[a],wf[j],ac2[a][j]);
    }
  }
#pragma unroll
  for (int j=0;j<8;j++){
    float bv=bout[h0+j];
#pragma unroll
    for (int a=0;a<4;a++)
      xout[(size_t)(g0+4*gsub+a)*256+128+h0+j]=__fadd_rn(ac2[a][j],bv);
  }
}

// ----------------------------------------------------------------
extern "C" void kernel_launch(void* const* d_in, const int* in_sizes, int n_in,
                              void* d_out, int out_size, void* d_ws, size_t ws_size,
                              hipStream_t stream) {
  const float* xyz  =(const float*)d_in[0];
  const float* feats=(const float*)d_in[1];
  const float* gW1  =(const float*)d_in[2];
  const float* gWout=(const float*)d_in[3];
  const float* fW1  =(const float*)d_in[4];
  const float* fb1  =(const float*)d_in[5];
  const float* fWout=(const float*)d_in[6];
  const float* fbout=(const float*)d_in[7];
  float* out=(float*)d_out;

  u16t* gidx16=(u16t*)d_ws;          // 1 MB
  float* xout = out + (size_t)B_*M_*3;

  fps_kernel <<<dim3(B_),          dim3(512), 0, stream>>>(xyz, out);
  knn_kernel <<<dim3((B_*M_)/4),   dim3(256), 0, stream>>>(xyz, out, gidx16);
  geo_kernel <<<dim3((B_*M_)/32),  dim3(256), 0, stream>>>(xyz, out, gidx16, gW1, gWout, xout);
  feat_kernel<<<dim3((B_*M_)/64),  dim3(256), 0, stream>>>(feats, gidx16, fW1, fb1, fWout, fbout, xout);
}

// Round 7
// 1331.163 us; speedup vs baseline: 2.2881x; 1.0006x over previous
//
#include <hip/hip_runtime.h>
#include <float.h>

#define B_ 16
#define N_ 4096
#define M_ 1024
#define K_ 32
#define FEAT_ 64
#define H_ 128
#define GEO_IN_ 160
#define GEO_MID_ 130
#define FEAT_IN_ 2048

typedef unsigned short u16t;

// ---- wave64 reductions in the VALU pipe (DPP), identity-preserving ----
#define DPP_STEP_MAX(ctrl) \
  t=(unsigned)__builtin_amdgcn_update_dpp((int)v,(int)v,(ctrl),0xf,0xf,false); \
  v=(t>v)?t:v;
#define DPP_STEP_MIN(ctrl) \
  t=(unsigned)__builtin_amdgcn_update_dpp((int)v,(int)v,(ctrl),0xf,0xf,false); \
  v=(t<v)?t:v;

__device__ __forceinline__ unsigned wave_max_u32(unsigned v){
  unsigned t;
  DPP_STEP_MAX(0x111) DPP_STEP_MAX(0x112) DPP_STEP_MAX(0x114) DPP_STEP_MAX(0x118)
  DPP_STEP_MAX(0x142) DPP_STEP_MAX(0x143)
  return (unsigned)__builtin_amdgcn_readlane((int)v,63);
}
__device__ __forceinline__ unsigned wave_min_u32(unsigned v){
  unsigned t;
  DPP_STEP_MIN(0x111) DPP_STEP_MIN(0x112) DPP_STEP_MIN(0x114) DPP_STEP_MIN(0x118)
  DPP_STEP_MIN(0x142) DPP_STEP_MIN(0x143)
  return (unsigned)__builtin_amdgcn_readlane((int)v,63);
}

// ---------------------------------------------------------------- FPS
// One block (256 thr = 4 waves, 1 wave/SIMD) per batch. 16 pts/thread in
// registers. Per step: dist update + local argmax -> 2x u32 DPP reduction ->
// owner lane publishes [key | coords] record to LDS (double-buffered) ->
// single barrier -> all threads merge 4 records (parallel LDS reads, cndmask
// tournament). Winner coords never round-trip through global or a dependent
// gather. Centroids buffered in LDS, bulk-written at the end.
// Semantics: max dist, tie -> smallest index; no FMA contraction in distance.
__global__ __launch_bounds__(256) void fps_kernel(
    const float* __restrict__ xyz, float* __restrict__ outc)
{
  const int b = blockIdx.x, tid = threadIdx.x;
  const int wv = tid >> 6;
  const float* xb = xyz + (size_t)b * (N_*3);
  __shared__ unsigned long long kkey[2][4];
  __shared__ __align__(16) float4 kxyz[2][4];
  __shared__ float clist[M_][3];          // 12 KB
  float px[16], py[16], pz[16], dd[16];
#pragma unroll
  for (int j=0;j<16;j++){
    int i = tid + 256*j;
    px[j]=xb[i*3]; py[j]=xb[i*3+1]; pz[j]=xb[i*3+2];
    dd[j]=FLT_MAX;
  }
  float lx=xb[0], ly=xb[1], lz=xb[2];
  if (tid==0){ clist[0][0]=lx; clist[0][1]=ly; clist[0][2]=lz; }
  for (int t=1;t<M_;t++){
    float bd=-FLT_MAX; int bi=0;
#pragma unroll
    for (int j=0;j<16;j++){
      float dx=__fsub_rn(px[j],lx), dy=__fsub_rn(py[j],ly), dz=__fsub_rn(pz[j],lz);
      float d=__fadd_rn(__fadd_rn(__fmul_rn(dx,dx),__fmul_rn(dy,dy)),__fmul_rn(dz,dz));
      d=fminf(dd[j],d); dd[j]=d;
      if (d>bd){ bd=d; bi=tid+256*j; }   // j asc => idx asc; strict > keeps first max
    }
    unsigned db=__float_as_uint(bd);          // bd>=0 => raw bits order-monotone
    unsigned smax=wave_max_u32(db);
    unsigned cand=(db==smax)?(unsigned)bi:0x7FFFFFFFu;
    unsigned sbi=wave_min_u32(cand);
    // owner lane (bi&255 == tid, always within this wave) publishes key+coords
    if ((unsigned)tid==(sbi&255u)){
      int oj=(int)(sbi>>8);
      kkey[t&1][wv]=((unsigned long long)smax<<32)|(unsigned)(0xFFFFFFFFu-sbi);
      kxyz[t&1][wv]=make_float4(px[oj],py[oj],pz[oj],0.f);
    }
    __syncthreads();
    // merge 4 wave candidates: higher dist wins, tie -> smaller index
    const unsigned long long* kp=kkey[t&1];
    const float4* cp=kxyz[t&1];
    unsigned long long k0=kp[0],k1=kp[1],k2=kp[2],k3=kp[3];
    float4 c0=cp[0],c1=cp[1],c2=cp[2],c3=cp[3];
    if (k1>k0){ k0=k1; c0=c1; }
    if (k3>k2){ k2=k3; c2=c3; }
    if (k2>k0){ k0=k2; c0=c2; }
    lx=c0.x; ly=c0.y; lz=c0.z;
    if (tid==0){ clist[t][0]=lx; clist[t][1]=ly; clist[t][2]=lz; }
  }
  __syncthreads();
  // bulk centroid write (one global pass, off the critical loop)
  for (int e=tid; e<M_; e+=256){
    size_t cb=((size_t)b*M_+(size_t)e)*3;
    outc[cb]=clist[e][0]; outc[cb+1]=clist[e][1]; outc[cb+2]=clist[e][2];
  }
}

// ---------------------------------------------------------------- KNN
// One wave per centroid. 64 dists/lane in registers. Selection: 2x u32 DPP
// (min dist, then min idx among ties) == stable top_k. Owner-lane rescan as
// exclusion + fminf min-tree + descending first-match index pass (exactly the
// same min value and smallest-index tie-break as a sequential scan).
__global__ __launch_bounds__(256) void knn_kernel(
    const float* __restrict__ xyz, const float* __restrict__ outc,
    u16t* __restrict__ gidx16)
{
  const int w = blockIdx.x*4 + (threadIdx.x>>6);
  const int lane = threadIdx.x & 63;
  const int b = w >> 10;
  const float* xb = xyz + (size_t)b*(N_*3);
  float cx=outc[(size_t)w*3], cy=outc[(size_t)w*3+1], cz=outc[(size_t)w*3+2];
  float c2=__fadd_rn(__fadd_rn(__fmul_rn(cx,cx),__fmul_rn(cy,cy)),__fmul_rn(cz,cz));
  float dl[64];
  float lv=FLT_MAX; int lj=0;
#pragma unroll
  for (int j=0;j<64;j++){
    int i = lane + 64*j;
    float xx=xb[i*3], xy=xb[i*3+1], xz=xb[i*3+2];
    float x2=__fadd_rn(__fadd_rn(__fmul_rn(xx,xx),__fmul_rn(xy,xy)),__fmul_rn(xz,xz));
    float dt=__fadd_rn(__fadd_rn(__fmul_rn(cx,xx),__fmul_rn(cy,xy)),__fmul_rn(cz,xz));
    float d=__fsub_rn(__fadd_rn(c2,x2),__fmul_rn(2.f,dt));
    dl[j]=d;
    if (d<lv){ lv=d; lj=j; }
  }
  const int wb = w*K_;
  for (int k=0;k<K_;k++){
    unsigned u=__float_as_uint(lv);
    u = (u&0x80000000u) ? ~u : (u|0x80000000u);   // order-preserving
    unsigned smin=wave_min_u32(u);
    unsigned cand=(u==smin)?(unsigned)(lane+64*lj):0xFFFFFFFFu;
    unsigned widx=wave_min_u32(cand);
    if (lane==0) gidx16[wb+k]=(u16t)widx;
    if ((widx & 63)==(unsigned)lane){
      int slot=(int)(widx>>6);
      // exclude consumed slot
#pragma unroll
      for (int j=0;j<64;j++) dl[j]=(j==slot)?FLT_MAX:dl[j];
      // pass 1: min value (fminf tree; exact same min as sequential scan)
      float m01[32];
#pragma unroll
      for (int j=0;j<32;j++) m01[j]=fminf(dl[2*j],dl[2*j+1]);
#pragma unroll
      for (int j=0;j<16;j++) m01[j]=fminf(m01[2*j],m01[2*j+1]);
#pragma unroll
      for (int j=0;j<8;j++)  m01[j]=fminf(m01[2*j],m01[2*j+1]);
#pragma unroll
      for (int j=0;j<4;j++)  m01[j]=fminf(m01[2*j],m01[2*j+1]);
      float nv=fminf(fminf(m01[0],m01[1]),fminf(m01[2],m01[3]));
      // pass 2: smallest index attaining the min
      int nj=63;
#pragma unroll
      for (int j=62;j>=0;j--) nj=(dl[j]==nv)?j:nj;
      lv=nv; lj=nj;
    }
  }
}

// ---------------------------------------------------------------- GEO fused (GEMM-style)
// (unchanged from round 6)
__global__ __launch_bounds__(256) void geo_kernel(
    const float* __restrict__ xyz, const float* __restrict__ outc,
    const u16t* __restrict__ gidx16, const float* __restrict__ W1,
    const float* __restrict__ Wout, float* __restrict__ xout)
{
  __shared__ float smem[160*33 + 64*128 + 32];
  float (*Es)[33]  = (float(*)[33])smem;
  float (*Hs)[33]  = (float(*)[33])smem;
  float (*Ws)[128] = (float(*)[128])(smem + 160*33);
  float* ssv = smem + 160*33 + 64*128;

  const int t=threadIdx.x;
  const int g0=blockIdx.x*32;
  for (int p=t; p<1024; p+=256){
    int g=p>>5, kk=p&31;
    int gg=g0+g, b=gg>>10;
    int idx=gidx16[gg*K_+kk];
    const float* pt = xyz + ((size_t)b*N_+(size_t)idx)*3;
    const float* cc = outc + (size_t)gg*3;
    float dx=__fsub_rn(pt[0],cc[0]);
    float dy=__fsub_rn(pt[1],cc[1]);
    float dz=__fsub_rn(pt[2],cc[2]);
    float sq=__fadd_rn(__fadd_rn(__fmul_rn(dx,dx),__fmul_rn(dy,dy)),__fmul_rn(dz,dz));
    int r=5*kk;
    Es[r][g]=dx; Es[r+1][g]=dy; Es[r+2][g]=dz;
    Es[r+3][g]=-1.f; Es[r+4][g]=__fmul_rn(-0.5f,sq);
  }
  const int gsub=t>>4, hsub=t&15, h0=hsub*8;
  const int hw=t>>1;
  float acc[2][8];
#pragma unroll
  for (int a=0;a<2;a++)
#pragma unroll
    for (int j=0;j<8;j++) acc[a][j]=0.f;
  __syncthreads();

  for (int c=0;c<3;c++){
    int i0=c*64;
    if (c<2){
      int fw0=(t&1)*32;
      const float* wr = W1 + (size_t)hw*GEO_IN_ + i0 + fw0;
      float4 wv[8];
#pragma unroll
      for (int e=0;e<8;e++) wv[e]=((const float4*)wr)[e];
#pragma unroll
      for (int e=0;e<8;e++){
        Ws[fw0+4*e+0][hw]=wv[e].x;
        Ws[fw0+4*e+1][hw]=wv[e].y;
        Ws[fw0+4*e+2][hw]=wv[e].z;
        Ws[fw0+4*e+3][hw]=wv[e].w;
      }
    } else {
      int fw0=(t&1)*16;
      const float* wr = W1 + (size_t)hw*GEO_IN_ + 128 + fw0;
      float4 wv[4];
#pragma unroll
      for (int e=0;e<4;e++) wv[e]=((const float4*)wr)[e];
#pragma unroll
      for (int e=0;e<4;e++){
        Ws[fw0+4*e+0][hw]=wv[e].x;
        Ws[fw0+4*e+1][hw]=wv[e].y;
        Ws[fw0+4*e+2][hw]=wv[e].z;
        Ws[fw0+4*e+3][hw]=wv[e].w;
      }
    }
    __syncthreads();
    int len=(c==2)?32:64;
    for (int k2=0;k2<len;k2++){
      float x0=Es[i0+k2][2*gsub], x1=Es[i0+k2][2*gsub+1];
      const float* wp=&Ws[k2][h0];
      float4 wa=*(const float4*)wp;
      float4 wb=*(const float4*)(wp+4);
      acc[0][0]=__builtin_fmaf(x0,wa.x,acc[0][0]);
      acc[0][1]=__builtin_fmaf(x0,wa.y,acc[0][1]);
      acc[0][2]=__builtin_fmaf(x0,wa.z,acc[0][2]);
      acc[0][3]=__builtin_fmaf(x0,wa.w,acc[0][3]);
      acc[0][4]=__builtin_fmaf(x0,wb.x,acc[0][4]);
      acc[0][5]=__builtin_fmaf(x0,wb.y,acc[0][5]);
      acc[0][6]=__builtin_fmaf(x0,wb.z,acc[0][6]);
      acc[0][7]=__builtin_fmaf(x0,wb.w,acc[0][7]);
      acc[1][0]=__builtin_fmaf(x1,wa.x,acc[1][0]);
      acc[1][1]=__builtin_fmaf(x1,wa.y,acc[1][1]);
      acc[1][2]=__builtin_fmaf(x1,wa.z,acc[1][2]);
      acc[1][3]=__builtin_fmaf(x1,wa.w,acc[1][3]);
      acc[1][4]=__builtin_fmaf(x1,wb.x,acc[1][4]);
      acc[1][5]=__builtin_fmaf(x1,wb.y,acc[1][5]);
      acc[1][6]=__builtin_fmaf(x1,wb.z,acc[1][6]);
      acc[1][7]=__builtin_fmaf(x1,wb.w,acc[1][7]);
    }
    __syncthreads();
  }
#pragma unroll
  for (int a=0;a<2;a++)
#pragma unroll
    for (int j=0;j<8;j++)
      Hs[h0+j][2*gsub+a]=acc[a][j];
  __syncthreads();
  if (t<32){
    float ss=0.f;
    for (int h=0;h<H_;h++){ float v=Hs[h][t]; ss=__builtin_fmaf(v,v,ss); }
    ssv[t]=__fmul_rn(-0.5f,ss);
  }
#pragma unroll
  for (int a=0;a<2;a++)
#pragma unroll
    for (int j=0;j<8;j++) acc[a][j]=0.f;
  for (int c=0;c<2;c++){
    int i0=c*64;
    int fw0=(t&1)*32;
    const float* wr = Wout + (size_t)hw*GEO_MID_ + i0 + fw0;
    float2 wv2[16];
#pragma unroll
    for (int e=0;e<16;e++) wv2[e]=((const float2*)wr)[e];
    __syncthreads();
#pragma unroll
    for (int e=0;e<16;e++){
      Ws[fw0+2*e+0][hw]=wv2[e].x;
      Ws[fw0+2*e+1][hw]=wv2[e].y;
    }
    __syncthreads();
    for (int k2=0;k2<64;k2++){
      float x0=Hs[i0+k2][2*gsub], x1=Hs[i0+k2][2*gsub+1];
      const float* wp=&Ws[k2][h0];
      float4 wa=*(const float4*)wp;
      float4 wb=*(const float4*)(wp+4);
      acc[0][0]=__builtin_fmaf(x0,wa.x,acc[0][0]);
      acc[0][1]=__builtin_fmaf(x0,wa.y,acc[0][1]);
      acc[0][2]=__builtin_fmaf(x0,wa.z,acc[0][2]);
      acc[0][3]=__builtin_fmaf(x0,wa.w,acc[0][3]);
      acc[0][4]=__builtin_fmaf(x0,wb.x,acc[0][4]);
      acc[0][5]=__builtin_fmaf(x0,wb.y,acc[0][5]);
      acc[0][6]=__builtin_fmaf(x0,wb.z,acc[0][6]);
      acc[0][7]=__builtin_fmaf(x0,wb.w,acc[0][7]);
      acc[1][0]=__builtin_fmaf(x1,wa.x,acc[1][0]);
      acc[1][1]=__builtin_fmaf(x1,wa.y,acc[1][1]);
      acc[1][2]=__builtin_fmaf(x1,wa.z,acc[1][2]);
      acc[1][3]=__builtin_fmaf(x1,wa.w,acc[1][3]);
      acc[1][4]=__builtin_fmaf(x1,wb.x,acc[1][4]);
      acc[1][5]=__builtin_fmaf(x1,wb.y,acc[1][5]);
      acc[1][6]=__builtin_fmaf(x1,wb.z,acc[1][6]);
      acc[1][7]=__builtin_fmaf(x1,wb.w,acc[1][7]);
    }
  }
#pragma unroll
  for (int j=0;j<8;j++){
    int o=h0+j;
    float2 we=*(const float2*)(Wout + (size_t)o*GEO_MID_ + 128);
#pragma unroll
    for (int a=0;a<2;a++){
      float v=acc[a][j];
      v=__builtin_fmaf(-1.f, we.x, v);
      v=__builtin_fmaf(ssv[2*gsub+a], we.y, v);
      xout[(size_t)(g0+2*gsub+a)*256 + o]=v;
    }
  }
}

// ---------------------------------------------------------------- FEAT fused
// (unchanged from round 6)
__global__ __launch_bounds__(256) void feat_kernel(
    const float* __restrict__ feats, const u16t* __restrict__ gidx16,
    const float* __restrict__ W1, const float* __restrict__ b1,
    const float* __restrict__ Wout, const float* __restrict__ bout,
    float* __restrict__ xout)
{
  __shared__ float smem[12800];                      // 51.2 KB
  float (*Xs)[68]  = (float(*)[68])smem;             // [64][68]
  float (*Ws)[128] = (float(*)[128])(smem + 64*68);  // [64][128]
  float (*Hs)[68]  = (float(*)[68])smem;             // [128][68] alias (post K-loop)
  float (*WoS)[128]= (float(*)[128])(smem + 128*68); // [32][128]
  const int t=threadIdx.x;
  const int g0=blockIdx.x*64;
  const int gsub=t>>4;
  const int h0=(t&15)*8;
  const int glx=t>>2, fq=(t&3)*16;
  const int hw=t>>1, fw0=(t&1)*32;
  const int fw1=(t&1)*16;
  const int gld=g0+glx, bld=gld>>10;
  float acc[4][8];
#pragma unroll
  for (int a=0;a<4;a++)
#pragma unroll
    for (int j=0;j<8;j++) acc[a][j]=0.f;

  for (int kk=0;kk<K_;kk++){
    int nidx=gidx16[gld*K_+kk];
    const float* fr=feats + ((size_t)bld*N_+(size_t)nidx)*FEAT_ + fq;
    float4 p[4];
#pragma unroll
    for (int e=0;e<4;e++) p[e]=((const float4*)fr)[e];
    const float* wr=W1 + (size_t)hw*FEAT_IN_ + kk*64 + fw0;
    float4 wv[8];
#pragma unroll
    for (int e=0;e<8;e++) wv[e]=((const float4*)wr)[e];
#pragma unroll
    for (int e=0;e<4;e++){
      Xs[fq+4*e+0][glx]=p[e].x;
      Xs[fq+4*e+1][glx]=p[e].y;
      Xs[fq+4*e+2][glx]=p[e].z;
      Xs[fq+4*e+3][glx]=p[e].w;
    }
#pragma unroll
    for (int e=0;e<8;e++){
      Ws[fw0+4*e+0][hw]=wv[e].x;
      Ws[fw0+4*e+1][hw]=wv[e].y;
      Ws[fw0+4*e+2][hw]=wv[e].z;
      Ws[fw0+4*e+3][hw]=wv[e].w;
    }
    __syncthreads();
#pragma unroll 4
    for (int k2=0;k2<64;k2++){
      float4 xv=*(const float4*)&Xs[k2][4*gsub];
      const float* wp=&Ws[k2][h0];
      float4 wa=*(const float4*)wp;
      float4 wb=*(const float4*)(wp+4);
      float xr[4]={xv.x,xv.y,xv.z,xv.w};
      float wf[8]={wa.x,wa.y,wa.z,wa.w,wb.x,wb.y,wb.z,wb.w};
#pragma unroll
      for (int a=0;a<4;a++)
#pragma unroll
        for (int j=0;j<8;j++)
          acc[a][j]=__builtin_fmaf(xr[a],wf[j],acc[a][j]);
    }
    __syncthreads();
  }
#pragma unroll
  for (int j=0;j<8;j++){
    float bv=b1[h0+j];
#pragma unroll
    for (int a=0;a<4;a++)
      Hs[h0+j][4*gsub+a]=fmaxf(__fadd_rn(acc[a][j],bv),0.f);
  }
  float ac2[4][8];
#pragma unroll
  for (int a=0;a<4;a++)
#pragma unroll
    for (int j=0;j<8;j++) ac2[a][j]=0.f;
  for (int c=0;c<4;c++){
    const float* wr2=Wout + (size_t)hw*H_ + c*32 + fw1;
    float4 w2[4];
#pragma unroll
    for (int e=0;e<4;e++) w2[e]=((const float4*)wr2)[e];
    __syncthreads();
#pragma unroll
    for (int e=0;e<4;e++){
      WoS[fw1+4*e+0][hw]=w2[e].x;
      WoS[fw1+4*e+1][hw]=w2[e].y;
      WoS[fw1+4*e+2][hw]=w2[e].z;
      WoS[fw1+4*e+3][hw]=w2[e].w;
    }
    __syncthreads();
#pragma unroll 4
    for (int k2=0;k2<32;k2++){
      float4 xv=*(const float4*)&Hs[c*32+k2][4*gsub];
      const float* wp=&WoS[k2][h0];
      float4 wa=*(const float4*)wp;
      float4 wb=*(const float4*)(wp+4);
      float xr[4]={xv.x,xv.y,xv.z,xv.w};
      float wf[8]={wa.x,wa.y,wa.z,wa.w,wb.x,wb.y,wb.z,wb.w};
#pragma unroll
      for (int a=0;a<4;a++)
#pragma unroll
        for (int j=0;j<8;j++)
          ac2[a][j]=__builtin_fmaf(xr[a],wf[j],ac2[a][j]);
    }
  }
#pragma unroll
  for (int j=0;j<8;j++){
    float bv=bout[h0+j];
#pragma unroll
    for (int a=0;a<4;a++)
      xout[(size_t)(g0+4*gsub+a)*256+128+h0+j]=__fadd_rn(ac2[a][j],bv);
  }
}

// ----------------------------------------------------------------
extern "C" void kernel_launch(void* const* d_in, const int* in_sizes, int n_in,
                              void* d_out, int out_size, void* d_ws, size_t ws_size,
                              hipStream_t stream) {
  const float* xyz  =(const float*)d_in[0];
  const float* feats=(const float*)d_in[1];
  const float* gW1  =(const float*)d_in[2];
  const float* gWout=(const float*)d_in[3];
  const float* fW1  =(const float*)d_in[4];
  const float* fb1  =(const float*)d_in[5];
  const float* fWout=(const float*)d_in[6];
  const float* fbout=(const float*)d_in[7];
  float* out=(float*)d_out;

  u16t* gidx16=(u16t*)d_ws;          // 1 MB
  float* xout = out + (size_t)B_*M_*3;

  fps_kernel <<<dim3(B_),          dim3(256), 0, stream>>>(xyz, out);
  knn_kernel <<<dim3((B_*M_)/4),   dim3(256), 0, stream>>>(xyz, out, gidx16);
  geo_kernel <<<dim3((B_*M_)/32),  dim3(256), 0, stream>>>(xyz, out, gidx16, gW1, gWout, xout);
  feat_kernel<<<dim3((B_*M_)/64),  dim3(256), 0, stream>>>(feats, gidx16, fW1, fb1, fWout, fbout, xout);
}